// Round 2
// baseline (821.436 us; speedup 1.0000x reference)
//
#include <hip/hip_runtime.h>

#define NF 128           // feature dim (IN_F == HID == 128)
#define MM_BM 64         // rows per GEMM block

// ---------------- integer-layout detection ----------------
// Harness may hand int64 inputs as raw int64 words or converted int32.
// In an int64 buffer every odd 32-bit word is a high word == 0 (indices < 2^31).
// In int32, odd words are random node indices. Probe 16 odd positions.
__global__ void detect_kernel(const int* __restrict__ ei, int ne, int* __restrict__ mode) {
    if (threadIdx.x == 0 && blockIdx.x == 0) {
        int step = ne / 32; if (step < 1) step = 1;
        int all0 = 1;
        for (int k = 0; k < 16; ++k) {
            int idx = 2 * k * step + 1;          // odd; < 2*ne words (valid in both layouts)
            if (ei[idx] != 0) { all0 = 0; break; }
        }
        *mode = all0;                            // 1 = int64 words, 0 = int32
    }
}

// ---------------- CSR build ----------------
__global__ void deg_kernel(const int* __restrict__ ei, int ne, int n,
                           const int* __restrict__ mode, int* __restrict__ cnt) {
    int m = *mode;
    for (int e = blockIdx.x * blockDim.x + threadIdx.x; e < ne; e += gridDim.x * blockDim.x) {
        int dst = m ? ei[2 * (ne + e)] : ei[ne + e];
        if ((unsigned)dst < (unsigned)n) atomicAdd(&cnt[dst], 1);
    }
}

__global__ void dis_kernel(const int* __restrict__ cnt, float* __restrict__ dis, int n) {
    int i = blockIdx.x * blockDim.x + threadIdx.x;
    if (i < n) dis[i] = rsqrtf((float)(cnt[i] + 1));   // +1 self-loop; deg >= 1 always
}

// inclusive scan of cnt -> rowptr[i+1] (per-block partial), block sums to bsum
__global__ __launch_bounds__(256) void scan1(const int* __restrict__ cnt, int* __restrict__ rowptr,
                                             int* __restrict__ bsum, int n) {
    __shared__ int sm[256];
    int i = blockIdx.x * 256 + threadIdx.x;
    int v = (i < n) ? cnt[i] : 0;
    sm[threadIdx.x] = v;
    __syncthreads();
    for (int off = 1; off < 256; off <<= 1) {
        int t = (threadIdx.x >= off) ? sm[threadIdx.x - off] : 0;
        __syncthreads();
        sm[threadIdx.x] += t;
        __syncthreads();
    }
    if (i < n) rowptr[i + 1] = sm[threadIdx.x];
    if (threadIdx.x == 255) bsum[blockIdx.x] = sm[255];
}

// exclusive scan of block sums (nb <= 512)
__global__ __launch_bounds__(512) void scan2(int* __restrict__ bsum, int nb) {
    __shared__ int sm[512];
    int v = (threadIdx.x < nb) ? bsum[threadIdx.x] : 0;
    sm[threadIdx.x] = v;
    __syncthreads();
    for (int off = 1; off < 512; off <<= 1) {
        int t = (threadIdx.x >= off) ? sm[threadIdx.x - off] : 0;
        __syncthreads();
        sm[threadIdx.x] += t;
        __syncthreads();
    }
    if (threadIdx.x < nb) bsum[threadIdx.x] = sm[threadIdx.x] - v;  // exclusive
}

__global__ void scan3(int* __restrict__ rowptr, const int* __restrict__ bsum, int n) {
    int i = blockIdx.x * 256 + threadIdx.x;
    if (i < n) rowptr[i + 1] += bsum[blockIdx.x];
    if (i == 0) rowptr[0] = 0;
}

__global__ void fill_init(const int* __restrict__ rowptr, int* __restrict__ fill, int n) {
    int i = blockIdx.x * blockDim.x + threadIdx.x;
    if (i < n) fill[i] = rowptr[i];
}

__global__ void fill_kernel(const int* __restrict__ ei, int ne, int n,
                            const int* __restrict__ mode, int* __restrict__ fill,
                            int* __restrict__ col) {
    int m = *mode;
    for (int e = blockIdx.x * blockDim.x + threadIdx.x; e < ne; e += gridDim.x * blockDim.x) {
        int src = m ? ei[2 * e] : ei[e];
        int dst = m ? ei[2 * (ne + e)] : ei[ne + e];
        if ((unsigned)dst >= (unsigned)n || (unsigned)src >= (unsigned)n) continue;
        int pos = atomicAdd(&fill[dst], 1);
        col[pos] = src;
    }
}

// ---------------- dense GEMM: out[i] = (A[i] @ W) * dis[i] ----------------
__global__ __launch_bounds__(256) void mm_kernel(const float* __restrict__ A, const float* __restrict__ W,
                                                 const float* __restrict__ dis, float* __restrict__ out,
                                                 int n) {
    __shared__ float sW[NF * NF];  // 64 KB
    int tid = threadIdx.x;
    int row0 = blockIdx.x * MM_BM;
    const float4* W4 = (const float4*)W;
    float4* sW4 = (float4*)sW;
#pragma unroll
    for (int i = 0; i < 16; ++i) sW4[tid + 256 * i] = W4[tid + 256 * i];
    __syncthreads();

    int tx = tid & 15, ty = tid >> 4;
    int colbase = tx * 8;
    int r0 = row0 + ty * 4;
    const float* Arow[4];
#pragma unroll
    for (int r = 0; r < 4; ++r) Arow[r] = A + (size_t)min(r0 + r, n - 1) * NF;

    float acc[4][8];
#pragma unroll
    for (int r = 0; r < 4; ++r)
#pragma unroll
        for (int c = 0; c < 8; ++c) acc[r][c] = 0.f;

    for (int k0 = 0; k0 < NF; k0 += 4) {
        float4 av[4];
#pragma unroll
        for (int r = 0; r < 4; ++r) av[r] = *(const float4*)(Arow[r] + k0);
#pragma unroll
        for (int kk = 0; kk < 4; ++kk) {
            float4 b0 = *(const float4*)&sW[(k0 + kk) * NF + colbase];
            float4 b1 = *(const float4*)&sW[(k0 + kk) * NF + colbase + 4];
#pragma unroll
            for (int r = 0; r < 4; ++r) {
                float a = (kk == 0) ? av[r].x : (kk == 1) ? av[r].y : (kk == 2) ? av[r].z : av[r].w;
                acc[r][0] = fmaf(a, b0.x, acc[r][0]);
                acc[r][1] = fmaf(a, b0.y, acc[r][1]);
                acc[r][2] = fmaf(a, b0.z, acc[r][2]);
                acc[r][3] = fmaf(a, b0.w, acc[r][3]);
                acc[r][4] = fmaf(a, b1.x, acc[r][4]);
                acc[r][5] = fmaf(a, b1.y, acc[r][5]);
                acc[r][6] = fmaf(a, b1.z, acc[r][6]);
                acc[r][7] = fmaf(a, b1.w, acc[r][7]);
            }
        }
    }
#pragma unroll
    for (int r = 0; r < 4; ++r) {
        int row = r0 + r;
        if (row < n) {
            float d = dis[row];
            float4 o0 = make_float4(acc[r][0] * d, acc[r][1] * d, acc[r][2] * d, acc[r][3] * d);
            float4 o1 = make_float4(acc[r][4] * d, acc[r][5] * d, acc[r][6] * d, acc[r][7] * d);
            *(float4*)&out[(size_t)row * NF + colbase] = o0;
            *(float4*)&out[(size_t)row * NF + colbase + 4] = o1;
        }
    }
}

// ---------------- SpMM: one wave per dst row ----------------
__global__ __launch_bounds__(256) void spmm_kernel(const float* __restrict__ hs, const int* __restrict__ rowptr,
                                                   const int* __restrict__ col, const float* __restrict__ dis,
                                                   const float* __restrict__ b, float* __restrict__ out,
                                                   int n, int do_relu) {
    int wid = (blockIdx.x * blockDim.x + threadIdx.x) >> 6;
    int lane = threadIdx.x & 63;
    if (wid >= n) return;
    int s = rowptr[wid], e = rowptr[wid + 1];

    float2 acc = *(const float2*)(hs + (size_t)wid * NF + 2 * lane);  // self-loop
    int i = s;
    for (; i + 4 <= e; i += 4) {
        int s0 = col[i], s1 = col[i + 1], s2 = col[i + 2], s3 = col[i + 3];
        float2 v0 = *(const float2*)(hs + (size_t)s0 * NF + 2 * lane);
        float2 v1 = *(const float2*)(hs + (size_t)s1 * NF + 2 * lane);
        float2 v2 = *(const float2*)(hs + (size_t)s2 * NF + 2 * lane);
        float2 v3 = *(const float2*)(hs + (size_t)s3 * NF + 2 * lane);
        acc.x += v0.x + v1.x + v2.x + v3.x;
        acc.y += v0.y + v1.y + v2.y + v3.y;
    }
    for (; i < e; ++i) {
        int s0 = col[i];
        float2 v0 = *(const float2*)(hs + (size_t)s0 * NF + 2 * lane);
        acc.x += v0.x;
        acc.y += v0.y;
    }
    float d = dis[wid];
    float2 bb = *(const float2*)(b + 2 * lane);
    float rx = fmaf(d, acc.x, bb.x);
    float ry = fmaf(d, acc.y, bb.y);
    if (do_relu) { rx = fmaxf(rx, 0.f); ry = fmaxf(ry, 0.f); }
    *(float2*)(out + (size_t)wid * NF + 2 * lane) = make_float2(rx, ry);
}

// ---------------- pooling over sorted batch ids ----------------
#define POOL_CHUNK 256
__global__ __launch_bounds__(128) void pool_kernel(const float* __restrict__ h, const int* __restrict__ batch,
                                                   const int* __restrict__ mode, int G,
                                                   float* __restrict__ psum, float* __restrict__ pcnt, int n) {
    int m = *mode;
    int f = threadIdx.x;  // feature 0..127
    int s = blockIdx.x * POOL_CHUNK;
    if (s >= n) return;
    int e = min(s + POOL_CHUNK, n);
    float acc = 0.f;
    int g_cur = m ? batch[2 * s] : batch[s];
    int run = 0;
    for (int i = s; i < e; ++i) {
        int g = m ? batch[2 * i] : batch[i];
        if (g != g_cur) {
            if ((unsigned)g_cur < (unsigned)G) {
                atomicAdd(&psum[(size_t)g_cur * NF + f], acc);
                if (f == 0) atomicAdd(&pcnt[g_cur], (float)run);
            }
            acc = 0.f; run = 0; g_cur = g;
        }
        acc += h[(size_t)i * NF + f];
        run++;
    }
    if ((unsigned)g_cur < (unsigned)G) {
        atomicAdd(&psum[(size_t)g_cur * NF + f], acc);
        if (f == 0) atomicAdd(&pcnt[g_cur], (float)run);
    }
}

// ---------------- head ----------------
__global__ __launch_bounds__(256) void final_kernel(const float* __restrict__ psum, const float* __restrict__ pcnt,
                                                    const float* __restrict__ Wl, const float* __restrict__ bl,
                                                    float* __restrict__ out, int ngraphs) {
    int wid = (blockIdx.x * blockDim.x + threadIdx.x) >> 6;
    int lane = threadIdx.x & 63;
    if (wid >= ngraphs) return;
    float inv = 1.0f / fmaxf(pcnt[wid], 1.0f);
    float p0 = psum[(size_t)wid * NF + lane] * inv;
    float p1 = psum[(size_t)wid * NF + 64 + lane] * inv;
    float o0 = p0 * Wl[lane * 2 + 0] + p1 * Wl[(lane + 64) * 2 + 0];
    float o1 = p0 * Wl[lane * 2 + 1] + p1 * Wl[(lane + 64) * 2 + 1];
    for (int off = 32; off; off >>= 1) {
        o0 += __shfl_down(o0, off);
        o1 += __shfl_down(o1, off);
    }
    if (lane == 0) {
        out[wid * 2 + 0] = o0 + bl[0];
        out[wid * 2 + 1] = o1 + bl[1];
    }
}

extern "C" void kernel_launch(void* const* d_in, const int* in_sizes, int n_in,
                              void* d_out, int out_size, void* d_ws, size_t ws_size,
                              hipStream_t stream) {
    const float* x  = (const float*)d_in[0];
    const int*   ei = (const int*)d_in[1];
    const int*   bt = (const int*)d_in[2];
    const float* W1 = (const float*)d_in[3];
    const float* b1 = (const float*)d_in[4];
    const float* W2 = (const float*)d_in[5];
    const float* b2 = (const float*)d_in[6];
    const float* W3 = (const float*)d_in[7];
    const float* b3 = (const float*)d_in[8];
    const float* Wl = (const float*)d_in[9];
    const float* bl = (const float*)d_in[10];
    float* out = (float*)d_out;

    const int n  = in_sizes[2];        // 100000 nodes
    const int ne = in_sizes[1] / 2;    // 1600000 edges
    const int G  = out_size / 2;       // 512 graphs

    size_t off = 0;
    auto alloc = [&](size_t bytes) { size_t o = off; off += (bytes + 255) & ~(size_t)255; return o; };
    char* ws = (char*)d_ws;
    float* bufA   = (float*)(ws + alloc((size_t)n * NF * 4));
    float* bufB   = (float*)(ws + alloc((size_t)n * NF * 4));
    int*   col    = (int*)  (ws + alloc((size_t)ne * 4));
    int*   rowptr = (int*)  (ws + alloc((size_t)(n + 1) * 4));
    int*   cnt    = (int*)  (ws + alloc((size_t)n * 4));
    int*   fill   = (int*)  (ws + alloc((size_t)n * 4));
    float* dis    = (float*)(ws + alloc((size_t)n * 4));
    int*   bsum   = (int*)  (ws + alloc(512 * 4));
    float* psum   = (float*)(ws + alloc((size_t)G * NF * 4));
    float* pcnt   = (float*)(ws + alloc((size_t)G * 4));
    int*   mode   = (int*)  (ws + alloc(256));
    (void)ws_size;

    const int nb = (n + 255) / 256;

    hipMemsetAsync(cnt, 0, (size_t)n * 4, stream);
    hipMemsetAsync(psum, 0, (size_t)G * NF * 4, stream);
    hipMemsetAsync(pcnt, 0, (size_t)G * 4, stream);

    detect_kernel<<<1, 64, 0, stream>>>(ei, ne, mode);

    deg_kernel<<<1024, 256, 0, stream>>>(ei, ne, n, mode, cnt);
    dis_kernel<<<nb, 256, 0, stream>>>(cnt, dis, n);
    scan1<<<nb, 256, 0, stream>>>(cnt, rowptr, bsum, n);
    scan2<<<1, 512, 0, stream>>>(bsum, nb);
    scan3<<<nb, 256, 0, stream>>>(rowptr, bsum, n);
    fill_init<<<nb, 256, 0, stream>>>(rowptr, fill, n);
    fill_kernel<<<1024, 256, 0, stream>>>(ei, ne, n, mode, fill, col);

    const int mm_grid = (n + MM_BM - 1) / MM_BM;
    const int sp_grid = (n + 3) / 4;

    mm_kernel<<<mm_grid, 256, 0, stream>>>(x, W1, dis, bufA, n);
    spmm_kernel<<<sp_grid, 256, 0, stream>>>(bufA, rowptr, col, dis, b1, bufB, n, 1);
    mm_kernel<<<mm_grid, 256, 0, stream>>>(bufB, W2, dis, bufA, n);
    spmm_kernel<<<sp_grid, 256, 0, stream>>>(bufA, rowptr, col, dis, b2, bufB, n, 1);
    mm_kernel<<<mm_grid, 256, 0, stream>>>(bufB, W3, dis, bufA, n);
    spmm_kernel<<<sp_grid, 256, 0, stream>>>(bufA, rowptr, col, dis, b3, bufB, n, 0);

    pool_kernel<<<(n + POOL_CHUNK - 1) / POOL_CHUNK, 128, 0, stream>>>(bufB, bt, mode, G, psum, pcnt, n);
    final_kernel<<<(G + 3) / 4, 256, 0, stream>>>(psum, pcnt, Wl, bl, out, G);
}

// Round 3
// 816.327 us; speedup vs baseline: 1.0063x; 1.0063x over previous
//
#include <hip/hip_runtime.h>

#define NF 128           // feature dim (IN_F == HID == 128)
#define NFU 64           // uints per row in bf16 (NF/2)
#define MM_BM 64         // rows per GEMM block
#define BUCKET_W 64      // dsts per bucket
#define BUCKET_CAP 2048  // max edges per bucket (mean 1024, sd ~32)

// ---------------- integer-layout detection ----------------
// int64 buffer: every odd 32-bit word is a high word == 0 (indices < 2^31).
__global__ void detect_kernel(const int* __restrict__ ei, int ne, int* __restrict__ mode) {
    if (threadIdx.x == 0 && blockIdx.x == 0) {
        int step = ne / 32; if (step < 1) step = 1;
        int all0 = 1;
        for (int k = 0; k < 16; ++k) {
            int idx = 2 * k * step + 1;
            if (ei[idx] != 0) { all0 = 0; break; }
        }
        *mode = all0;                            // 1 = int64 words, 0 = int32
    }
}

// ---------------- CSR build ----------------
__global__ void deg_kernel(const int* __restrict__ ei, int ne, int n,
                           const int* __restrict__ mode, int* __restrict__ cnt) {
    int m = *mode;
    for (int e = blockIdx.x * blockDim.x + threadIdx.x; e < ne; e += gridDim.x * blockDim.x) {
        int dst = m ? ei[2 * (ne + e)] : ei[ne + e];
        if ((unsigned)dst < (unsigned)n) atomicAdd(&cnt[dst], 1);
    }
}

__global__ void dis_kernel(const int* __restrict__ cnt, float* __restrict__ dis, int n) {
    int i = blockIdx.x * blockDim.x + threadIdx.x;
    if (i < n) dis[i] = rsqrtf((float)(cnt[i] + 1));   // +1 self-loop
}

// inclusive scan of cnt -> rowptr[i+1] (per-block partial), block sums to bsum
__global__ __launch_bounds__(256) void scan1(const int* __restrict__ cnt, int* __restrict__ rowptr,
                                             int* __restrict__ bsum, int n) {
    __shared__ int sm[256];
    int i = blockIdx.x * 256 + threadIdx.x;
    int v = (i < n) ? cnt[i] : 0;
    sm[threadIdx.x] = v;
    __syncthreads();
    for (int off = 1; off < 256; off <<= 1) {
        int t = (threadIdx.x >= off) ? sm[threadIdx.x - off] : 0;
        __syncthreads();
        sm[threadIdx.x] += t;
        __syncthreads();
    }
    if (i < n) rowptr[i + 1] = sm[threadIdx.x];
    if (threadIdx.x == 255) bsum[blockIdx.x] = sm[255];
}

__global__ __launch_bounds__(512) void scan2(int* __restrict__ bsum, int nb) {
    __shared__ int sm[512];
    int v = (threadIdx.x < nb) ? bsum[threadIdx.x] : 0;
    sm[threadIdx.x] = v;
    __syncthreads();
    for (int off = 1; off < 512; off <<= 1) {
        int t = (threadIdx.x >= off) ? sm[threadIdx.x - off] : 0;
        __syncthreads();
        sm[threadIdx.x] += t;
        __syncthreads();
    }
    if (threadIdx.x < nb) bsum[threadIdx.x] = sm[threadIdx.x] - v;  // exclusive
}

__global__ void scan3(int* __restrict__ rowptr, const int* __restrict__ bsum, int n) {
    int i = blockIdx.x * 256 + threadIdx.x;
    if (i < n) rowptr[i + 1] += bsum[blockIdx.x];
    if (i == 0) rowptr[0] = 0;
}

// bucket fill pointers start at rowptr[b * BUCKET_W]
__global__ void bfill_init(const int* __restrict__ rowptr, int* __restrict__ bfill, int nbuk, int n) {
    int b = blockIdx.x * blockDim.x + threadIdx.x;
    if (b < nbuk) {
        int d = b * BUCKET_W;
        bfill[b] = rowptr[d < n ? d : n];
    }
}

// scatter (src,dst) pairs into dst-buckets; bucket regions are contiguous in pairbuf
__global__ void pairscatter(const int* __restrict__ ei, int ne, int n,
                            const int* __restrict__ mode, int* __restrict__ bfill,
                            uint2* __restrict__ pairbuf) {
    int m = *mode;
    for (int e = blockIdx.x * blockDim.x + threadIdx.x; e < ne; e += gridDim.x * blockDim.x) {
        int src = m ? ei[2 * e] : ei[e];
        int dst = m ? ei[2 * (ne + e)] : ei[ne + e];
        if ((unsigned)dst >= (unsigned)n || (unsigned)src >= (unsigned)n) continue;
        int pos = atomicAdd(&bfill[dst >> 6], 1);
        pairbuf[pos] = make_uint2((unsigned)src, (unsigned)dst);
    }
}

// per-bucket counting sort: LDS scatter, contiguous col write
__global__ __launch_bounds__(256) void bucket_sort(const uint2* __restrict__ pairbuf,
                                                   const int* __restrict__ rowptr,
                                                   int* __restrict__ col, int n) {
    __shared__ int lfill[BUCKET_W];
    __shared__ int lcol[BUCKET_CAP];
    int tid = threadIdx.x;
    int r0 = blockIdx.x * BUCKET_W;
    int base = rowptr[r0];
    int rend = r0 + BUCKET_W; if (rend > n) rend = n;
    int end = rowptr[rend];
    int cntb = end - base;
    if (tid < BUCKET_W) {
        int d = r0 + tid;
        lfill[tid] = (d < n) ? (rowptr[d] - base) : cntb;
    }
    __syncthreads();
    for (int i = base + tid; i < end; i += 256) {
        uint2 p = pairbuf[i];
        int slot = atomicAdd(&lfill[p.y - (unsigned)r0], 1);
        if (slot < BUCKET_CAP) lcol[slot] = (int)p.x;
    }
    __syncthreads();
    for (int i = tid; i < cntb; i += 256) col[base + i] = lcol[i];
}

// ---------------- bf16 helpers ----------------
__device__ inline unsigned pack_bf16(float a, float b) {
    unsigned ua = __float_as_uint(a), ub = __float_as_uint(b);
    ua = (ua + 0x7fffu + ((ua >> 16) & 1u)) >> 16;
    ub = (ub + 0x7fffu + ((ub >> 16) & 1u)) >> 16;
    return ua | (ub << 16);
}

// ---------------- dense GEMM: hs[i] = bf16( (A[i] @ W) * dis[i] ) ----------------
// W (128x128, 64KB) in LDS; A fp32 float4 loads; output packed bf16 (2 feats/uint).
__global__ __launch_bounds__(256) void mm_kernel(const float* __restrict__ A, const float* __restrict__ W,
                                                 const float* __restrict__ dis, unsigned* __restrict__ hs,
                                                 int n) {
    __shared__ float sW[NF * NF];  // 64 KB
    int tid = threadIdx.x;
    int row0 = blockIdx.x * MM_BM;
    const float4* W4 = (const float4*)W;
    float4* sW4 = (float4*)sW;
#pragma unroll
    for (int i = 0; i < 16; ++i) sW4[tid + 256 * i] = W4[tid + 256 * i];
    __syncthreads();

    int tx = tid & 15, ty = tid >> 4;
    int colbase = tx * 8;
    int r0 = row0 + ty * 4;
    const float* Arow[4];
#pragma unroll
    for (int r = 0; r < 4; ++r) Arow[r] = A + (size_t)min(r0 + r, n - 1) * NF;

    float acc[4][8];
#pragma unroll
    for (int r = 0; r < 4; ++r)
#pragma unroll
        for (int c = 0; c < 8; ++c) acc[r][c] = 0.f;

    for (int k0 = 0; k0 < NF; k0 += 4) {
        float4 av[4];
#pragma unroll
        for (int r = 0; r < 4; ++r) av[r] = *(const float4*)(Arow[r] + k0);
#pragma unroll
        for (int kk = 0; kk < 4; ++kk) {
            float4 b0 = *(const float4*)&sW[(k0 + kk) * NF + colbase];
            float4 b1 = *(const float4*)&sW[(k0 + kk) * NF + colbase + 4];
#pragma unroll
            for (int r = 0; r < 4; ++r) {
                float a = (kk == 0) ? av[r].x : (kk == 1) ? av[r].y : (kk == 2) ? av[r].z : av[r].w;
                acc[r][0] = fmaf(a, b0.x, acc[r][0]);
                acc[r][1] = fmaf(a, b0.y, acc[r][1]);
                acc[r][2] = fmaf(a, b0.z, acc[r][2]);
                acc[r][3] = fmaf(a, b0.w, acc[r][3]);
                acc[r][4] = fmaf(a, b1.x, acc[r][4]);
                acc[r][5] = fmaf(a, b1.y, acc[r][5]);
                acc[r][6] = fmaf(a, b1.z, acc[r][6]);
                acc[r][7] = fmaf(a, b1.w, acc[r][7]);
            }
        }
    }
#pragma unroll
    for (int r = 0; r < 4; ++r) {
        int row = r0 + r;
        if (row < n) {
            float d = dis[row];
            unsigned p0 = pack_bf16(acc[r][0] * d, acc[r][1] * d);
            unsigned p1 = pack_bf16(acc[r][2] * d, acc[r][3] * d);
            unsigned p2 = pack_bf16(acc[r][4] * d, acc[r][5] * d);
            unsigned p3 = pack_bf16(acc[r][6] * d, acc[r][7] * d);
            *(uint4*)&hs[(size_t)row * NFU + tx * 4] = make_uint4(p0, p1, p2, p3);
        }
    }
}

// ---------------- SpMM: one wave per dst row, bf16 gathers ----------------
// out[i] = act( dis[i] * (sum_{e: dst=i} hs[col_e] + hs[i]) + b )
__global__ __launch_bounds__(256) void spmm_kernel(const unsigned* __restrict__ hs, const int* __restrict__ rowptr,
                                                   const int* __restrict__ col, const float* __restrict__ dis,
                                                   const float* __restrict__ b, float* __restrict__ out,
                                                   int n, int do_relu) {
    int wid = (blockIdx.x * blockDim.x + threadIdx.x) >> 6;
    int lane = threadIdx.x & 63;
    if (wid >= n) return;
    int s = rowptr[wid], e = rowptr[wid + 1];

    unsigned sv = hs[(size_t)wid * NFU + lane];   // self-loop
    float ax = __uint_as_float(sv << 16);
    float ay = __uint_as_float(sv & 0xFFFF0000u);
    int i = s;
    for (; i + 4 <= e; i += 4) {
        int s0 = col[i], s1 = col[i + 1], s2 = col[i + 2], s3 = col[i + 3];
        unsigned v0 = hs[(size_t)s0 * NFU + lane];
        unsigned v1 = hs[(size_t)s1 * NFU + lane];
        unsigned v2 = hs[(size_t)s2 * NFU + lane];
        unsigned v3 = hs[(size_t)s3 * NFU + lane];
        ax += __uint_as_float(v0 << 16) + __uint_as_float(v1 << 16)
            + __uint_as_float(v2 << 16) + __uint_as_float(v3 << 16);
        ay += __uint_as_float(v0 & 0xFFFF0000u) + __uint_as_float(v1 & 0xFFFF0000u)
            + __uint_as_float(v2 & 0xFFFF0000u) + __uint_as_float(v3 & 0xFFFF0000u);
    }
    for (; i < e; ++i) {
        unsigned v0 = hs[(size_t)col[i] * NFU + lane];
        ax += __uint_as_float(v0 << 16);
        ay += __uint_as_float(v0 & 0xFFFF0000u);
    }
    float d = dis[wid];
    float2 bb = *(const float2*)(b + 2 * lane);
    float rx = fmaf(d, ax, bb.x);
    float ry = fmaf(d, ay, bb.y);
    if (do_relu) { rx = fmaxf(rx, 0.f); ry = fmaxf(ry, 0.f); }
    *(float2*)(out + (size_t)wid * NF + 2 * lane) = make_float2(rx, ry);
}

// ---------------- pooling over sorted batch ids ----------------
#define POOL_CHUNK 256
__global__ __launch_bounds__(128) void pool_kernel(const float* __restrict__ h, const int* __restrict__ batch,
                                                   const int* __restrict__ mode, int G,
                                                   float* __restrict__ psum, float* __restrict__ pcnt, int n) {
    int m = *mode;
    int f = threadIdx.x;
    int s = blockIdx.x * POOL_CHUNK;
    if (s >= n) return;
    int e = min(s + POOL_CHUNK, n);
    float acc = 0.f;
    int g_cur = m ? batch[2 * s] : batch[s];
    int run = 0;
    for (int i = s; i < e; ++i) {
        int g = m ? batch[2 * i] : batch[i];
        if (g != g_cur) {
            if ((unsigned)g_cur < (unsigned)G) {
                atomicAdd(&psum[(size_t)g_cur * NF + f], acc);
                if (f == 0) atomicAdd(&pcnt[g_cur], (float)run);
            }
            acc = 0.f; run = 0; g_cur = g;
        }
        acc += h[(size_t)i * NF + f];
        run++;
    }
    if ((unsigned)g_cur < (unsigned)G) {
        atomicAdd(&psum[(size_t)g_cur * NF + f], acc);
        if (f == 0) atomicAdd(&pcnt[g_cur], (float)run);
    }
}

// ---------------- head ----------------
__global__ __launch_bounds__(256) void final_kernel(const float* __restrict__ psum, const float* __restrict__ pcnt,
                                                    const float* __restrict__ Wl, const float* __restrict__ bl,
                                                    float* __restrict__ out, int ngraphs) {
    int wid = (blockIdx.x * blockDim.x + threadIdx.x) >> 6;
    int lane = threadIdx.x & 63;
    if (wid >= ngraphs) return;
    float inv = 1.0f / fmaxf(pcnt[wid], 1.0f);
    float p0 = psum[(size_t)wid * NF + lane] * inv;
    float p1 = psum[(size_t)wid * NF + 64 + lane] * inv;
    float o0 = p0 * Wl[lane * 2 + 0] + p1 * Wl[(lane + 64) * 2 + 0];
    float o1 = p0 * Wl[lane * 2 + 1] + p1 * Wl[(lane + 64) * 2 + 1];
    for (int off = 32; off; off >>= 1) {
        o0 += __shfl_down(o0, off);
        o1 += __shfl_down(o1, off);
    }
    if (lane == 0) {
        out[wid * 2 + 0] = o0 + bl[0];
        out[wid * 2 + 1] = o1 + bl[1];
    }
}

extern "C" void kernel_launch(void* const* d_in, const int* in_sizes, int n_in,
                              void* d_out, int out_size, void* d_ws, size_t ws_size,
                              hipStream_t stream) {
    const float* x  = (const float*)d_in[0];
    const int*   ei = (const int*)d_in[1];
    const int*   bt = (const int*)d_in[2];
    const float* W1 = (const float*)d_in[3];
    const float* b1 = (const float*)d_in[4];
    const float* W2 = (const float*)d_in[5];
    const float* b2 = (const float*)d_in[6];
    const float* W3 = (const float*)d_in[7];
    const float* b3 = (const float*)d_in[8];
    const float* Wl = (const float*)d_in[9];
    const float* bl = (const float*)d_in[10];
    float* out = (float*)d_out;

    const int n  = in_sizes[2];        // 100000 nodes
    const int ne = in_sizes[1] / 2;    // 1600000 edges
    const int G  = out_size / 2;       // 512 graphs
    const int nbuk = (n + BUCKET_W - 1) / BUCKET_W;

    size_t off = 0;
    auto alloc = [&](size_t bytes) { size_t o = off; off += (bytes + 255) & ~(size_t)255; return o; };
    char* ws = (char*)d_ws;
    float*    hF     = (float*)   (ws + alloc((size_t)n * NF * 4));   // fp32 conv outputs
    unsigned* hsB    = (unsigned*)(ws + alloc((size_t)n * NFU * 4));  // bf16 gather buffer
    uint2*    pairbuf= (uint2*)   (ws + alloc((size_t)ne * 8));
    int*      col    = (int*)     (ws + alloc((size_t)ne * 4));
    int*      rowptr = (int*)     (ws + alloc((size_t)(n + 1) * 4));
    int*      cnt    = (int*)     (ws + alloc((size_t)n * 4));
    int*      bfill  = (int*)     (ws + alloc((size_t)nbuk * 4));
    float*    dis    = (float*)   (ws + alloc((size_t)n * 4));
    int*      bsum   = (int*)     (ws + alloc(512 * 4));
    float*    psum   = (float*)   (ws + alloc((size_t)G * NF * 4));
    float*    pcnt   = (float*)   (ws + alloc((size_t)G * 4));
    int*      mode   = (int*)     (ws + alloc(256));
    (void)ws_size;

    const int nb = (n + 255) / 256;

    hipMemsetAsync(cnt, 0, (size_t)n * 4, stream);
    hipMemsetAsync(psum, 0, (size_t)G * NF * 4, stream);
    hipMemsetAsync(pcnt, 0, (size_t)G * 4, stream);

    detect_kernel<<<1, 64, 0, stream>>>(ei, ne, mode);

    // CSR build: degree -> rowptr -> bucketed pair scatter -> per-bucket sort
    deg_kernel<<<1024, 256, 0, stream>>>(ei, ne, n, mode, cnt);
    dis_kernel<<<nb, 256, 0, stream>>>(cnt, dis, n);
    scan1<<<nb, 256, 0, stream>>>(cnt, rowptr, bsum, n);
    scan2<<<1, 512, 0, stream>>>(bsum, nb);
    scan3<<<nb, 256, 0, stream>>>(rowptr, bsum, n);
    bfill_init<<<(nbuk + 255) / 256, 256, 0, stream>>>(rowptr, bfill, nbuk, n);
    pairscatter<<<2048, 256, 0, stream>>>(ei, ne, n, mode, bfill, pairbuf);
    bucket_sort<<<nbuk, 256, 0, stream>>>(pairbuf, rowptr, col, n);

    const int mm_grid = (n + MM_BM - 1) / MM_BM;
    const int sp_grid = (n + 3) / 4;

    mm_kernel<<<mm_grid, 256, 0, stream>>>(x, W1, dis, hsB, n);
    spmm_kernel<<<sp_grid, 256, 0, stream>>>(hsB, rowptr, col, dis, b1, hF, n, 1);
    mm_kernel<<<mm_grid, 256, 0, stream>>>(hF, W2, dis, hsB, n);
    spmm_kernel<<<sp_grid, 256, 0, stream>>>(hsB, rowptr, col, dis, b2, hF, n, 1);
    mm_kernel<<<mm_grid, 256, 0, stream>>>(hF, W3, dis, hsB, n);
    spmm_kernel<<<sp_grid, 256, 0, stream>>>(hsB, rowptr, col, dis, b3, hF, n, 0);

    pool_kernel<<<(n + POOL_CHUNK - 1) / POOL_CHUNK, 128, 0, stream>>>(hF, bt, mode, G, psum, pcnt, n);
    final_kernel<<<(G + 3) / 4, 256, 0, stream>>>(psum, pcnt, Wl, bl, out, G);
}

// Round 4
// 516.027 us; speedup vs baseline: 1.5918x; 1.5819x over previous
//
#include <hip/hip_runtime.h>

#define NF 128            // feature dim
#define NFU 64            // uints per bf16 row (NF/2)
#define MM_BM 64          // rows per GEMM block
#define BW 128            // dst rows per bucket
#define KMAX 1024         // max buckets (n <= 131072)
#define CAP 3072          // max edges per bucket (mean 2048, sd 45)
#define CHUNK 8192        // edges per block in hist/scatter

// ---------------- integer-layout detection ----------------
// int64 buffer: every odd 32-bit word is a high word == 0 (indices < 2^31).
__global__ void detect_kernel(const int* __restrict__ ei, int ne, int* __restrict__ mode) {
    if (threadIdx.x == 0 && blockIdx.x == 0) {
        int step = ne / 32; if (step < 1) step = 1;
        int all0 = 1;
        for (int k = 0; k < 16; ++k) {
            int idx = 2 * k * step + 1;
            if (ei[idx] != 0) { all0 = 0; break; }
        }
        *mode = all0;                            // 1 = int64 words, 0 = int32
    }
}

// ---------------- pass 1a: per-bucket edge counts ----------------
__global__ __launch_bounds__(256) void hist_kernel(const int* __restrict__ ei, int ne, int n,
                                                   const int* __restrict__ mode, int* __restrict__ btotal,
                                                   int K) {
    __shared__ int hist[KMAX];
    int m = *mode;
    int tid = threadIdx.x;
    for (int k = tid; k < K; k += 256) hist[k] = 0;
    __syncthreads();
    int base = blockIdx.x * CHUNK;
    int end = min(base + CHUNK, ne);
    for (int e = base + tid; e < end; e += 256) {
        int dst = m ? ei[2 * (ne + e)] : ei[ne + e];
        if ((unsigned)dst < (unsigned)n) atomicAdd(&hist[dst >> 7], 1);
    }
    __syncthreads();
    for (int k = tid; k < K; k += 256)
        if (hist[k]) atomicAdd(&btotal[k], hist[k]);
}

// ---------------- pass 1b: prefix over bucket totals ----------------
__global__ __launch_bounds__(1024) void scanK(const int* __restrict__ btotal, int* __restrict__ bbase,
                                              int* __restrict__ gcur, int K) {
    __shared__ int sm[1024];
    int tid = threadIdx.x;
    int v = (tid < K) ? btotal[tid] : 0;
    sm[tid] = v;
    __syncthreads();
    for (int off = 1; off < 1024; off <<= 1) {
        int t = (tid >= off) ? sm[tid - off] : 0;
        __syncthreads();
        sm[tid] += t;
        __syncthreads();
    }
    if (tid < K) {
        int excl = sm[tid] - v;
        bbase[tid] = excl;
        gcur[tid] = excl;
        if (tid == K - 1) bbase[K] = sm[tid];
    }
}

// ---------------- pass 1c: bucketed pair scatter (LDS-binned bursts) ----------------
__global__ __launch_bounds__(256) void scatter_kernel(const int* __restrict__ ei, int ne, int n,
                                                      const int* __restrict__ mode, int* __restrict__ gcur,
                                                      uint2* __restrict__ pairbuf, int K) {
    __shared__ int cur[KMAX];
    int m = *mode;
    int tid = threadIdx.x;
    for (int k = tid; k < K; k += 256) cur[k] = 0;
    __syncthreads();
    int base = blockIdx.x * CHUNK;
    int end = min(base + CHUNK, ne);
    // count
    for (int e = base + tid; e < end; e += 256) {
        int dst = m ? ei[2 * (ne + e)] : ei[ne + e];
        if ((unsigned)dst < (unsigned)n) atomicAdd(&cur[dst >> 7], 1);
    }
    __syncthreads();
    // reserve: cur[k] <- global base for this block's items in bucket k
    for (int k = tid; k < K; k += 256) {
        int c = cur[k];
        cur[k] = c ? atomicAdd(&gcur[k], c) : 0;
    }
    __syncthreads();
    // scatter
    for (int e = base + tid; e < end; e += 256) {
        int src = m ? ei[2 * e] : ei[e];
        int dst = m ? ei[2 * (ne + e)] : ei[ne + e];
        if ((unsigned)dst >= (unsigned)n || (unsigned)src >= (unsigned)n) continue;
        int pos = atomicAdd(&cur[dst >> 7], 1);
        pairbuf[pos] = make_uint2((unsigned)src, (unsigned)dst);
    }
}

// ---------------- pass 2: per-bucket counting sort + degree/rowptr/dis ----------------
__global__ __launch_bounds__(256) void sort_kernel(const uint2* __restrict__ pairbuf,
                                                   const int* __restrict__ bbase,
                                                   int* __restrict__ rowptr, float* __restrict__ dis,
                                                   int* __restrict__ col, int n, int K) {
    __shared__ uint2 spair[CAP];   // 24 KB
    __shared__ int lcol[CAP];      // 12 KB
    __shared__ int dcnt[BW];
    __shared__ int pref[BW];
    int tid = threadIdx.x;
    int b = blockIdx.x;
    int r0 = b * BW;
    int base = bbase[b];
    int end = bbase[b + 1];
    int cntb = end - base;
    if (cntb > CAP) cntb = CAP;    // safety (statistically impossible here)

    for (int i = tid; i < cntb; i += 256) spair[i] = pairbuf[base + i];
    if (tid < BW) dcnt[tid] = 0;
    __syncthreads();
    for (int i = tid; i < cntb; i += 256) atomicAdd(&dcnt[spair[i].y & (BW - 1)], 1);
    __syncthreads();
    if (tid < BW) pref[tid] = dcnt[tid];
    __syncthreads();
    for (int off = 1; off < BW; off <<= 1) {
        int t = (tid < BW && tid >= off) ? pref[tid - off] : 0;
        __syncthreads();
        if (tid < BW) pref[tid] += t;
        __syncthreads();
    }
    if (tid < BW) {
        int d = r0 + tid;
        if (d < n) {
            int excl = pref[tid] - dcnt[tid];
            rowptr[d] = base + excl;
            dis[d] = rsqrtf((float)(dcnt[tid] + 1));   // +1 self-loop
        }
    }
    if (b == K - 1 && tid == 0) rowptr[n] = end;
    // cursors = bucket-local exclusive prefix
    if (tid < BW) dcnt[tid] = pref[tid] - dcnt[tid];
    __syncthreads();
    for (int i = tid; i < cntb; i += 256) {
        int slot = atomicAdd(&dcnt[spair[i].y & (BW - 1)], 1);
        if (slot < CAP) lcol[slot] = (int)spair[i].x;
    }
    __syncthreads();
    for (int i = tid; i < cntb; i += 256) col[base + i] = lcol[i];
}

// ---------------- bf16 helpers ----------------
__device__ inline unsigned pack_bf16(float a, float b) {
    unsigned ua = __float_as_uint(a), ub = __float_as_uint(b);
    ua = (ua + 0x7fffu + ((ua >> 16) & 1u)) >> 16;
    ub = (ub + 0x7fffu + ((ub >> 16) & 1u)) >> 16;
    return ua | (ub << 16);
}

// ---------------- dense GEMM: hs[i] = bf16( (A[i] @ W) * dis[i] ) ----------------
__global__ __launch_bounds__(256) void mm_kernel(const float* __restrict__ A, const float* __restrict__ W,
                                                 const float* __restrict__ dis, unsigned* __restrict__ hs,
                                                 int n) {
    __shared__ float sW[NF * NF];  // 64 KB
    int tid = threadIdx.x;
    int row0 = blockIdx.x * MM_BM;
    const float4* W4 = (const float4*)W;
    float4* sW4 = (float4*)sW;
#pragma unroll
    for (int i = 0; i < 16; ++i) sW4[tid + 256 * i] = W4[tid + 256 * i];
    __syncthreads();

    int tx = tid & 15, ty = tid >> 4;
    int colbase = tx * 8;
    int r0 = row0 + ty * 4;
    const float* Arow[4];
#pragma unroll
    for (int r = 0; r < 4; ++r) Arow[r] = A + (size_t)min(r0 + r, n - 1) * NF;

    float acc[4][8];
#pragma unroll
    for (int r = 0; r < 4; ++r)
#pragma unroll
        for (int c = 0; c < 8; ++c) acc[r][c] = 0.f;

    for (int k0 = 0; k0 < NF; k0 += 4) {
        float4 av[4];
#pragma unroll
        for (int r = 0; r < 4; ++r) av[r] = *(const float4*)(Arow[r] + k0);
#pragma unroll
        for (int kk = 0; kk < 4; ++kk) {
            float4 b0 = *(const float4*)&sW[(k0 + kk) * NF + colbase];
            float4 b1 = *(const float4*)&sW[(k0 + kk) * NF + colbase + 4];
#pragma unroll
            for (int r = 0; r < 4; ++r) {
                float a = (kk == 0) ? av[r].x : (kk == 1) ? av[r].y : (kk == 2) ? av[r].z : av[r].w;
                acc[r][0] = fmaf(a, b0.x, acc[r][0]);
                acc[r][1] = fmaf(a, b0.y, acc[r][1]);
                acc[r][2] = fmaf(a, b0.z, acc[r][2]);
                acc[r][3] = fmaf(a, b0.w, acc[r][3]);
                acc[r][4] = fmaf(a, b1.x, acc[r][4]);
                acc[r][5] = fmaf(a, b1.y, acc[r][5]);
                acc[r][6] = fmaf(a, b1.z, acc[r][6]);
                acc[r][7] = fmaf(a, b1.w, acc[r][7]);
            }
        }
    }
#pragma unroll
    for (int r = 0; r < 4; ++r) {
        int row = r0 + r;
        if (row < n) {
            float d = dis[row];
            unsigned p0 = pack_bf16(acc[r][0] * d, acc[r][1] * d);
            unsigned p1 = pack_bf16(acc[r][2] * d, acc[r][3] * d);
            unsigned p2 = pack_bf16(acc[r][4] * d, acc[r][5] * d);
            unsigned p3 = pack_bf16(acc[r][6] * d, acc[r][7] * d);
            *(uint4*)&hs[(size_t)row * NFU + tx * 4] = make_uint4(p0, p1, p2, p3);
        }
    }
}

// ---------------- SpMM: one wave per dst row, bf16 gathers, deep MLP ----------------
__global__ __launch_bounds__(256) void spmm_kernel(const unsigned* __restrict__ hs, const int* __restrict__ rowptr,
                                                   const int* __restrict__ col, const float* __restrict__ dis,
                                                   const float* __restrict__ b, float* __restrict__ out,
                                                   int n, int do_relu) {
    int wid = (blockIdx.x * blockDim.x + threadIdx.x) >> 6;
    int lane = threadIdx.x & 63;
    if (wid >= n) return;
    int s = rowptr[wid], e = rowptr[wid + 1];
    int deg = e - s;

    unsigned sv = hs[(size_t)wid * NFU + lane];   // self-loop
    float ax = __uint_as_float(sv << 16);
    float ay = __uint_as_float(sv & 0xFFFF0000u);

    // one coalesced load grabs up to 64 neighbor indices for the whole wave
    int m64 = min(deg, 64);
    int cidx = (lane < m64) ? col[s + lane] : 0;

    int j = 0;
    for (; j + 8 <= m64; j += 8) {
        int c0 = __shfl(cidx, j + 0), c1 = __shfl(cidx, j + 1);
        int c2 = __shfl(cidx, j + 2), c3 = __shfl(cidx, j + 3);
        int c4 = __shfl(cidx, j + 4), c5 = __shfl(cidx, j + 5);
        int c6 = __shfl(cidx, j + 6), c7 = __shfl(cidx, j + 7);
        unsigned v0 = hs[(size_t)c0 * NFU + lane];
        unsigned v1 = hs[(size_t)c1 * NFU + lane];
        unsigned v2 = hs[(size_t)c2 * NFU + lane];
        unsigned v3 = hs[(size_t)c3 * NFU + lane];
        unsigned v4 = hs[(size_t)c4 * NFU + lane];
        unsigned v5 = hs[(size_t)c5 * NFU + lane];
        unsigned v6 = hs[(size_t)c6 * NFU + lane];
        unsigned v7 = hs[(size_t)c7 * NFU + lane];
        ax += __uint_as_float(v0 << 16) + __uint_as_float(v1 << 16)
            + __uint_as_float(v2 << 16) + __uint_as_float(v3 << 16)
            + __uint_as_float(v4 << 16) + __uint_as_float(v5 << 16)
            + __uint_as_float(v6 << 16) + __uint_as_float(v7 << 16);
        ay += __uint_as_float(v0 & 0xFFFF0000u) + __uint_as_float(v1 & 0xFFFF0000u)
            + __uint_as_float(v2 & 0xFFFF0000u) + __uint_as_float(v3 & 0xFFFF0000u)
            + __uint_as_float(v4 & 0xFFFF0000u) + __uint_as_float(v5 & 0xFFFF0000u)
            + __uint_as_float(v6 & 0xFFFF0000u) + __uint_as_float(v7 & 0xFFFF0000u);
    }
    for (; j < m64; ++j) {
        int c = __shfl(cidx, j);
        unsigned v = hs[(size_t)c * NFU + lane];
        ax += __uint_as_float(v << 16);
        ay += __uint_as_float(v & 0xFFFF0000u);
    }
    for (int i = s + 64; i < e; ++i) {                // rare: deg > 64
        unsigned v = hs[(size_t)col[i] * NFU + lane];
        ax += __uint_as_float(v << 16);
        ay += __uint_as_float(v & 0xFFFF0000u);
    }

    float d = dis[wid];
    float2 bb = *(const float2*)(b + 2 * lane);
    float rx = fmaf(d, ax, bb.x);
    float ry = fmaf(d, ay, bb.y);
    if (do_relu) { rx = fmaxf(rx, 0.f); ry = fmaxf(ry, 0.f); }
    *(float2*)(out + (size_t)wid * NF + 2 * lane) = make_float2(rx, ry);
}

// ---------------- pooling over sorted batch ids ----------------
#define POOL_CHUNK 256
__global__ __launch_bounds__(128) void pool_kernel(const float* __restrict__ h, const int* __restrict__ batch,
                                                   const int* __restrict__ mode, int G,
                                                   float* __restrict__ psum, float* __restrict__ pcnt, int n) {
    int m = *mode;
    int f = threadIdx.x;
    int s = blockIdx.x * POOL_CHUNK;
    if (s >= n) return;
    int e = min(s + POOL_CHUNK, n);
    float acc = 0.f;
    int g_cur = m ? batch[2 * s] : batch[s];
    int run = 0;
    for (int i = s; i < e; ++i) {
        int g = m ? batch[2 * i] : batch[i];
        if (g != g_cur) {
            if ((unsigned)g_cur < (unsigned)G) {
                atomicAdd(&psum[(size_t)g_cur * NF + f], acc);
                if (f == 0) atomicAdd(&pcnt[g_cur], (float)run);
            }
            acc = 0.f; run = 0; g_cur = g;
        }
        acc += h[(size_t)i * NF + f];
        run++;
    }
    if ((unsigned)g_cur < (unsigned)G) {
        atomicAdd(&psum[(size_t)g_cur * NF + f], acc);
        if (f == 0) atomicAdd(&pcnt[g_cur], (float)run);
    }
}

// ---------------- head ----------------
__global__ __launch_bounds__(256) void final_kernel(const float* __restrict__ psum, const float* __restrict__ pcnt,
                                                    const float* __restrict__ Wl, const float* __restrict__ bl,
                                                    float* __restrict__ out, int ngraphs) {
    int wid = (blockIdx.x * blockDim.x + threadIdx.x) >> 6;
    int lane = threadIdx.x & 63;
    if (wid >= ngraphs) return;
    float inv = 1.0f / fmaxf(pcnt[wid], 1.0f);
    float p0 = psum[(size_t)wid * NF + lane] * inv;
    float p1 = psum[(size_t)wid * NF + 64 + lane] * inv;
    float o0 = p0 * Wl[lane * 2 + 0] + p1 * Wl[(lane + 64) * 2 + 0];
    float o1 = p0 * Wl[lane * 2 + 1] + p1 * Wl[(lane + 64) * 2 + 1];
    for (int off = 32; off; off >>= 1) {
        o0 += __shfl_down(o0, off);
        o1 += __shfl_down(o1, off);
    }
    if (lane == 0) {
        out[wid * 2 + 0] = o0 + bl[0];
        out[wid * 2 + 1] = o1 + bl[1];
    }
}

extern "C" void kernel_launch(void* const* d_in, const int* in_sizes, int n_in,
                              void* d_out, int out_size, void* d_ws, size_t ws_size,
                              hipStream_t stream) {
    const float* x  = (const float*)d_in[0];
    const int*   ei = (const int*)d_in[1];
    const int*   bt = (const int*)d_in[2];
    const float* W1 = (const float*)d_in[3];
    const float* b1 = (const float*)d_in[4];
    const float* W2 = (const float*)d_in[5];
    const float* b2 = (const float*)d_in[6];
    const float* W3 = (const float*)d_in[7];
    const float* b3 = (const float*)d_in[8];
    const float* Wl = (const float*)d_in[9];
    const float* bl = (const float*)d_in[10];
    float* out = (float*)d_out;

    const int n  = in_sizes[2];        // 100000 nodes
    const int ne = in_sizes[1] / 2;    // 1600000 edges
    const int G  = out_size / 2;       // 512 graphs
    const int K  = (n + BW - 1) / BW;  // 782 buckets

    size_t off = 0;
    auto alloc = [&](size_t bytes) { size_t o = off; off += (bytes + 255) & ~(size_t)255; return o; };
    char* ws = (char*)d_ws;
    float*    hF     = (float*)   (ws + alloc((size_t)n * NF * 4));   // fp32 conv outputs
    unsigned* hsB    = (unsigned*)(ws + alloc((size_t)n * NFU * 4));  // bf16 gather buffer
    uint2*    pairbuf= (uint2*)   (ws + alloc((size_t)ne * 8));
    int*      col    = (int*)     (ws + alloc((size_t)ne * 4));
    int*      rowptr = (int*)     (ws + alloc((size_t)(n + 1) * 4));
    float*    dis    = (float*)   (ws + alloc((size_t)n * 4));
    int*      btotal = (int*)     (ws + alloc((size_t)(K + 1) * 4));
    int*      bbase  = (int*)     (ws + alloc((size_t)(K + 1) * 4));
    int*      gcur   = (int*)     (ws + alloc((size_t)(K + 1) * 4));
    float*    psum   = (float*)   (ws + alloc((size_t)G * NF * 4));
    float*    pcnt   = (float*)   (ws + alloc((size_t)G * 4));
    int*      mode   = (int*)     (ws + alloc(256));
    (void)ws_size;

    const int nchunks = (ne + CHUNK - 1) / CHUNK;

    hipMemsetAsync(btotal, 0, (size_t)(K + 1) * 4, stream);
    hipMemsetAsync(psum, 0, (size_t)G * NF * 4, stream);
    hipMemsetAsync(pcnt, 0, (size_t)G * 4, stream);

    detect_kernel<<<1, 64, 0, stream>>>(ei, ne, mode);

    // CSR build: bucket hist -> prefix -> binned scatter -> per-bucket sort (+deg/rowptr/dis)
    hist_kernel<<<nchunks, 256, 0, stream>>>(ei, ne, n, mode, btotal, K);
    scanK<<<1, 1024, 0, stream>>>(btotal, bbase, gcur, K);
    scatter_kernel<<<nchunks, 256, 0, stream>>>(ei, ne, n, mode, gcur, pairbuf, K);
    sort_kernel<<<K, 256, 0, stream>>>(pairbuf, bbase, rowptr, dis, col, n, K);

    const int mm_grid = (n + MM_BM - 1) / MM_BM;
    const int sp_grid = (n + 3) / 4;

    mm_kernel<<<mm_grid, 256, 0, stream>>>(x, W1, dis, hsB, n);
    spmm_kernel<<<sp_grid, 256, 0, stream>>>(hsB, rowptr, col, dis, b1, hF, n, 1);
    mm_kernel<<<mm_grid, 256, 0, stream>>>(hF, W2, dis, hsB, n);
    spmm_kernel<<<sp_grid, 256, 0, stream>>>(hsB, rowptr, col, dis, b2, hF, n, 1);
    mm_kernel<<<mm_grid, 256, 0, stream>>>(hF, W3, dis, hsB, n);
    spmm_kernel<<<sp_grid, 256, 0, stream>>>(hsB, rowptr, col, dis, b3, hF, n, 0);

    pool_kernel<<<(n + POOL_CHUNK - 1) / POOL_CHUNK, 128, 0, stream>>>(hF, bt, mode, G, psum, pcnt, n);
    final_kernel<<<(G + 3) / 4, 256, 0, stream>>>(psum, pcnt, Wl, bl, out, G);
}

// Round 5
// 448.373 us; speedup vs baseline: 1.8320x; 1.1509x over previous
//
#include <hip/hip_runtime.h>

#define NF 128            // feature dim
#define NFU 64            // uints per bf16 row (NF/2)
#define MM_BM 64          // rows per GEMM block
#define BW 128            // dst rows per bucket
#define KMAX 1024         // max buckets (n <= 131072)
#define CAP 3072          // max edges per bucket (mean 2048, sd 45)
#define CHUNK 8192        // edges per block in hist/scatter

// ---------------- integer-layout detection ----------------
// int64 buffer: every odd 32-bit word is a high word == 0 (indices < 2^31).
__global__ void detect_kernel(const int* __restrict__ ei, int ne, int* __restrict__ mode) {
    if (threadIdx.x == 0 && blockIdx.x == 0) {
        int step = ne / 32; if (step < 1) step = 1;
        int all0 = 1;
        for (int k = 0; k < 16; ++k) {
            int idx = 2 * k * step + 1;
            if (ei[idx] != 0) { all0 = 0; break; }
        }
        *mode = all0;                            // 1 = int64 words, 0 = int32
    }
}

// ---------------- pass 1a: per-bucket edge counts ----------------
__global__ __launch_bounds__(256) void hist_kernel(const int* __restrict__ ei, int ne, int n,
                                                   const int* __restrict__ mode, int* __restrict__ btotal,
                                                   int K) {
    __shared__ int hist[KMAX];
    int m = *mode;
    int tid = threadIdx.x;
    for (int k = tid; k < K; k += 256) hist[k] = 0;
    __syncthreads();
    int base = blockIdx.x * CHUNK;
    int end = min(base + CHUNK, ne);
    for (int e = base + tid; e < end; e += 256) {
        int dst = m ? ei[2 * (ne + e)] : ei[ne + e];
        if ((unsigned)dst < (unsigned)n) atomicAdd(&hist[dst >> 7], 1);
    }
    __syncthreads();
    for (int k = tid; k < K; k += 256)
        if (hist[k]) atomicAdd(&btotal[k], hist[k]);
}

// ---------------- pass 1b: prefix over bucket totals ----------------
__global__ __launch_bounds__(1024) void scanK(const int* __restrict__ btotal, int* __restrict__ bbase,
                                              int* __restrict__ gcur, int K) {
    __shared__ int sm[1024];
    int tid = threadIdx.x;
    int v = (tid < K) ? btotal[tid] : 0;
    sm[tid] = v;
    __syncthreads();
    for (int off = 1; off < 1024; off <<= 1) {
        int t = (tid >= off) ? sm[tid - off] : 0;
        __syncthreads();
        sm[tid] += t;
        __syncthreads();
    }
    if (tid < K) {
        int excl = sm[tid] - v;
        bbase[tid] = excl;
        gcur[tid] = excl;
        if (tid == K - 1) bbase[K] = sm[tid];
    }
}

// ---------------- pass 1c: bucketed pair scatter (LDS-binned bursts) ----------------
__global__ __launch_bounds__(256) void scatter_kernel(const int* __restrict__ ei, int ne, int n,
                                                      const int* __restrict__ mode, int* __restrict__ gcur,
                                                      uint2* __restrict__ pairbuf, int K) {
    __shared__ int cur[KMAX];
    int m = *mode;
    int tid = threadIdx.x;
    for (int k = tid; k < K; k += 256) cur[k] = 0;
    __syncthreads();
    int base = blockIdx.x * CHUNK;
    int end = min(base + CHUNK, ne);
    for (int e = base + tid; e < end; e += 256) {
        int dst = m ? ei[2 * (ne + e)] : ei[ne + e];
        if ((unsigned)dst < (unsigned)n) atomicAdd(&cur[dst >> 7], 1);
    }
    __syncthreads();
    for (int k = tid; k < K; k += 256) {
        int c = cur[k];
        cur[k] = c ? atomicAdd(&gcur[k], c) : 0;
    }
    __syncthreads();
    for (int e = base + tid; e < end; e += 256) {
        int src = m ? ei[2 * e] : ei[e];
        int dst = m ? ei[2 * (ne + e)] : ei[ne + e];
        if ((unsigned)dst >= (unsigned)n || (unsigned)src >= (unsigned)n) continue;
        int pos = atomicAdd(&cur[dst >> 7], 1);
        pairbuf[pos] = make_uint2((unsigned)src, (unsigned)dst);
    }
}

// ---------------- pass 2: per-bucket counting sort + degree/rowptr/dis ----------------
__global__ __launch_bounds__(256) void sort_kernel(const uint2* __restrict__ pairbuf,
                                                   const int* __restrict__ bbase,
                                                   int* __restrict__ rowptr, float* __restrict__ dis,
                                                   int* __restrict__ col, int n, int K) {
    __shared__ uint2 spair[CAP];
    __shared__ int lcol[CAP];
    __shared__ int dcnt[BW];
    __shared__ int pref[BW];
    int tid = threadIdx.x;
    int b = blockIdx.x;
    int r0 = b * BW;
    int base = bbase[b];
    int end = bbase[b + 1];
    int cntb = end - base;
    if (cntb > CAP) cntb = CAP;

    for (int i = tid; i < cntb; i += 256) spair[i] = pairbuf[base + i];
    if (tid < BW) dcnt[tid] = 0;
    __syncthreads();
    for (int i = tid; i < cntb; i += 256) atomicAdd(&dcnt[spair[i].y & (BW - 1)], 1);
    __syncthreads();
    if (tid < BW) pref[tid] = dcnt[tid];
    __syncthreads();
    for (int off = 1; off < BW; off <<= 1) {
        int t = (tid < BW && tid >= off) ? pref[tid - off] : 0;
        __syncthreads();
        if (tid < BW) pref[tid] += t;
        __syncthreads();
    }
    if (tid < BW) {
        int d = r0 + tid;
        if (d < n) {
            int excl = pref[tid] - dcnt[tid];
            rowptr[d] = base + excl;
            dis[d] = rsqrtf((float)(dcnt[tid] + 1));
        }
    }
    if (b == K - 1 && tid == 0) rowptr[n] = end;
    if (tid < BW) dcnt[tid] = pref[tid] - dcnt[tid];
    __syncthreads();
    for (int i = tid; i < cntb; i += 256) {
        int slot = atomicAdd(&dcnt[spair[i].y & (BW - 1)], 1);
        if (slot < CAP) lcol[slot] = (int)spair[i].x;
    }
    __syncthreads();
    for (int i = tid; i < cntb; i += 256) col[base + i] = lcol[i];
}

// ---------------- bf16 helpers ----------------
__device__ inline unsigned pack_bf16(float a, float b) {
    unsigned ua = __float_as_uint(a), ub = __float_as_uint(b);
    ua = (ua + 0x7fffu + ((ua >> 16) & 1u)) >> 16;
    ub = (ub + 0x7fffu + ((ub >> 16) & 1u)) >> 16;
    return ua | (ub << 16);
}
__device__ inline float bflo(unsigned u) { return __uint_as_float(u << 16); }
__device__ inline float bfhi(unsigned u) { return __uint_as_float(u & 0xFFFF0000u); }

// ---------------- dense GEMM: hs[i] = bf16( (A[i] @ W) * dis[i] ) ----------------
__global__ __launch_bounds__(256) void mm_kernel(const float* __restrict__ A, const float* __restrict__ W,
                                                 const float* __restrict__ dis, unsigned* __restrict__ hs,
                                                 int n) {
    __shared__ float sW[NF * NF];
    int tid = threadIdx.x;
    int row0 = blockIdx.x * MM_BM;
    const float4* W4 = (const float4*)W;
    float4* sW4 = (float4*)sW;
#pragma unroll
    for (int i = 0; i < 16; ++i) sW4[tid + 256 * i] = W4[tid + 256 * i];
    __syncthreads();

    int tx = tid & 15, ty = tid >> 4;
    int colbase = tx * 8;
    int r0 = row0 + ty * 4;
    const float* Arow[4];
#pragma unroll
    for (int r = 0; r < 4; ++r) Arow[r] = A + (size_t)min(r0 + r, n - 1) * NF;

    float acc[4][8];
#pragma unroll
    for (int r = 0; r < 4; ++r)
#pragma unroll
        for (int c = 0; c < 8; ++c) acc[r][c] = 0.f;

    for (int k0 = 0; k0 < NF; k0 += 4) {
        float4 av[4];
#pragma unroll
        for (int r = 0; r < 4; ++r) av[r] = *(const float4*)(Arow[r] + k0);
#pragma unroll
        for (int kk = 0; kk < 4; ++kk) {
            float4 b0 = *(const float4*)&sW[(k0 + kk) * NF + colbase];
            float4 b1 = *(const float4*)&sW[(k0 + kk) * NF + colbase + 4];
#pragma unroll
            for (int r = 0; r < 4; ++r) {
                float a = (kk == 0) ? av[r].x : (kk == 1) ? av[r].y : (kk == 2) ? av[r].z : av[r].w;
                acc[r][0] = fmaf(a, b0.x, acc[r][0]);
                acc[r][1] = fmaf(a, b0.y, acc[r][1]);
                acc[r][2] = fmaf(a, b0.z, acc[r][2]);
                acc[r][3] = fmaf(a, b0.w, acc[r][3]);
                acc[r][4] = fmaf(a, b1.x, acc[r][4]);
                acc[r][5] = fmaf(a, b1.y, acc[r][5]);
                acc[r][6] = fmaf(a, b1.z, acc[r][6]);
                acc[r][7] = fmaf(a, b1.w, acc[r][7]);
            }
        }
    }
#pragma unroll
    for (int r = 0; r < 4; ++r) {
        int row = r0 + r;
        if (row < n) {
            float d = dis[row];
            unsigned p0 = pack_bf16(acc[r][0] * d, acc[r][1] * d);
            unsigned p1 = pack_bf16(acc[r][2] * d, acc[r][3] * d);
            unsigned p2 = pack_bf16(acc[r][4] * d, acc[r][5] * d);
            unsigned p3 = pack_bf16(acc[r][6] * d, acc[r][7] * d);
            *(uint4*)&hs[(size_t)row * NFU + tx * 4] = make_uint4(p0, p1, p2, p3);
        }
    }
}

// ---------------- SpMM: one wave per dst row; 4 neighbor-groups x 16 lanes x uint4 ----------------
// One vmem instruction gathers 4 neighbors x 256B = 1KB.
__global__ __launch_bounds__(256) void spmm_kernel(const unsigned* __restrict__ hs, const int* __restrict__ rowptr,
                                                   const int* __restrict__ col, const float* __restrict__ dis,
                                                   const float* __restrict__ b, float* __restrict__ out,
                                                   int n, int do_relu) {
    int wid = (blockIdx.x * blockDim.x + threadIdx.x) >> 6;
    int lane = threadIdx.x & 63;
    if (wid >= n) return;
    int s = rowptr[wid], e = rowptr[wid + 1];
    int deg = e - s;
    int group = lane >> 4, fl = lane & 15;   // group: which neighbor; fl: 16B feature slice

    float acc[8];
    if (group == 0) {   // self-loop counted once
        uint4 sv = *(const uint4*)(hs + (size_t)wid * NFU + fl * 4);
        acc[0] = bflo(sv.x); acc[1] = bfhi(sv.x);
        acc[2] = bflo(sv.y); acc[3] = bfhi(sv.y);
        acc[4] = bflo(sv.z); acc[5] = bfhi(sv.z);
        acc[6] = bflo(sv.w); acc[7] = bfhi(sv.w);
    } else {
#pragma unroll
        for (int k = 0; k < 8; ++k) acc[k] = 0.f;
    }

    int m64 = min(deg, 64);
    int cidx = (lane < m64) ? col[s + lane] : 0;

    for (int j0 = 0; j0 < m64; j0 += 4) {
        int c = __shfl(cidx, j0 + group);
        if (j0 + group < m64) {
            uint4 v = *(const uint4*)(hs + (size_t)c * NFU + fl * 4);
            acc[0] += bflo(v.x); acc[1] += bfhi(v.x);
            acc[2] += bflo(v.y); acc[3] += bfhi(v.y);
            acc[4] += bflo(v.z); acc[5] += bfhi(v.z);
            acc[6] += bflo(v.w); acc[7] += bfhi(v.w);
        }
    }
    for (int i = s + 64 + group; i < e; i += 4) {   // rare tail: deg > 64
        int c = col[i];
        uint4 v = *(const uint4*)(hs + (size_t)c * NFU + fl * 4);
        acc[0] += bflo(v.x); acc[1] += bfhi(v.x);
        acc[2] += bflo(v.y); acc[3] += bfhi(v.y);
        acc[4] += bflo(v.z); acc[5] += bfhi(v.z);
        acc[6] += bflo(v.w); acc[7] += bfhi(v.w);
    }

#pragma unroll
    for (int k = 0; k < 8; ++k) {
        acc[k] += __shfl_xor(acc[k], 16);
        acc[k] += __shfl_xor(acc[k], 32);
    }

    if (lane < 16) {
        float d = dis[wid];
        float4 bb0 = *(const float4*)(b + fl * 8);
        float4 bb1 = *(const float4*)(b + fl * 8 + 4);
        float o[8];
        o[0] = fmaf(d, acc[0], bb0.x); o[1] = fmaf(d, acc[1], bb0.y);
        o[2] = fmaf(d, acc[2], bb0.z); o[3] = fmaf(d, acc[3], bb0.w);
        o[4] = fmaf(d, acc[4], bb1.x); o[5] = fmaf(d, acc[5], bb1.y);
        o[6] = fmaf(d, acc[6], bb1.z); o[7] = fmaf(d, acc[7], bb1.w);
        if (do_relu) {
#pragma unroll
            for (int k = 0; k < 8; ++k) o[k] = fmaxf(o[k], 0.f);
        }
        *(float4*)(out + (size_t)wid * NF + fl * 8)     = make_float4(o[0], o[1], o[2], o[3]);
        *(float4*)(out + (size_t)wid * NF + fl * 8 + 4) = make_float4(o[4], o[5], o[6], o[7]);
    }
}

// ---------------- graph boundaries from sorted batch ----------------
__global__ void gbounds_kernel(const int* __restrict__ batch, const int* __restrict__ mode,
                               int* __restrict__ gstart, int n, int G) {
    int m = *mode;
    int i = blockIdx.x * blockDim.x + threadIdx.x;
    if (i >= n) return;
    int g1 = m ? batch[2 * i] : batch[i];
    int g2 = (i == n - 1) ? G : (m ? batch[2 * (i + 1)] : batch[i + 1]);
    if ((unsigned)g1 > (unsigned)G) g1 = G;
    if ((unsigned)g2 > (unsigned)G) g2 = G;
    if (i == 0) for (int g = 0; g <= g1; ++g) gstart[g] = 0;
    for (int g = g1 + 1; g <= g2; ++g) gstart[g] = i + 1;
}

// ---------------- fused mean-pool + head: one block per graph ----------------
__global__ __launch_bounds__(256) void poolhead_kernel(const float* __restrict__ h, const int* __restrict__ gstart,
                                                       const float* __restrict__ Wl, const float* __restrict__ bl,
                                                       float* __restrict__ out, int G) {
    __shared__ float4 sacc[8][32];
    int g = blockIdx.x;
    int s = gstart[g], e = gstart[g + 1];
    int tid = threadIdx.x;
    int rg = tid >> 5;     // 8 parallel row-groups
    int fl = tid & 31;     // float4 feature slice

    float4 acc = make_float4(0.f, 0.f, 0.f, 0.f);
    for (int i = s + rg; i < e; i += 8) {
        float4 v = *(const float4*)(h + (size_t)i * NF + fl * 4);
        acc.x += v.x; acc.y += v.y; acc.z += v.z; acc.w += v.w;
    }
    sacc[rg][fl] = acc;
    __syncthreads();
    if (tid < 32) {
        float4 t = sacc[0][fl];
#pragma unroll
        for (int r = 1; r < 8; ++r) {
            float4 u = sacc[r][fl];
            t.x += u.x; t.y += u.y; t.z += u.z; t.w += u.w;
        }
        float inv = 1.0f / fmaxf((float)(e - s), 1.0f);
        int f0 = fl * 4;
        float o0 = t.x * inv * Wl[(f0 + 0) * 2] + t.y * inv * Wl[(f0 + 1) * 2]
                 + t.z * inv * Wl[(f0 + 2) * 2] + t.w * inv * Wl[(f0 + 3) * 2];
        float o1 = t.x * inv * Wl[(f0 + 0) * 2 + 1] + t.y * inv * Wl[(f0 + 1) * 2 + 1]
                 + t.z * inv * Wl[(f0 + 2) * 2 + 1] + t.w * inv * Wl[(f0 + 3) * 2 + 1];
#pragma unroll
        for (int off = 16; off; off >>= 1) {
            o0 += __shfl_down(o0, off, 32);
            o1 += __shfl_down(o1, off, 32);
        }
        if (fl == 0) {
            out[g * 2 + 0] = o0 + bl[0];
            out[g * 2 + 1] = o1 + bl[1];
        }
    }
}

extern "C" void kernel_launch(void* const* d_in, const int* in_sizes, int n_in,
                              void* d_out, int out_size, void* d_ws, size_t ws_size,
                              hipStream_t stream) {
    const float* x  = (const float*)d_in[0];
    const int*   ei = (const int*)d_in[1];
    const int*   bt = (const int*)d_in[2];
    const float* W1 = (const float*)d_in[3];
    const float* b1 = (const float*)d_in[4];
    const float* W2 = (const float*)d_in[5];
    const float* b2 = (const float*)d_in[6];
    const float* W3 = (const float*)d_in[7];
    const float* b3 = (const float*)d_in[8];
    const float* Wl = (const float*)d_in[9];
    const float* bl = (const float*)d_in[10];
    float* out = (float*)d_out;

    const int n  = in_sizes[2];        // 100000 nodes
    const int ne = in_sizes[1] / 2;    // 1600000 edges
    const int G  = out_size / 2;       // 512 graphs
    const int K  = (n + BW - 1) / BW;  // 782 buckets

    size_t off = 0;
    auto alloc = [&](size_t bytes) { size_t o = off; off += (bytes + 255) & ~(size_t)255; return o; };
    char* ws = (char*)d_ws;
    float*    hF     = (float*)   (ws + alloc((size_t)n * NF * 4));
    unsigned* hsB    = (unsigned*)(ws + alloc((size_t)n * NFU * 4));
    uint2*    pairbuf= (uint2*)   (ws + alloc((size_t)ne * 8));
    int*      col    = (int*)     (ws + alloc((size_t)ne * 4));
    int*      rowptr = (int*)     (ws + alloc((size_t)(n + 1) * 4));
    float*    dis    = (float*)   (ws + alloc((size_t)n * 4));
    int*      btotal = (int*)     (ws + alloc((size_t)(K + 1) * 4));
    int*      bbase  = (int*)     (ws + alloc((size_t)(K + 1) * 4));
    int*      gcur   = (int*)     (ws + alloc((size_t)(K + 1) * 4));
    int*      gstart = (int*)     (ws + alloc((size_t)(G + 1) * 4));
    int*      mode   = (int*)     (ws + alloc(256));
    (void)ws_size;

    const int nchunks = (ne + CHUNK - 1) / CHUNK;

    hipMemsetAsync(btotal, 0, (size_t)(K + 1) * 4, stream);

    detect_kernel<<<1, 64, 0, stream>>>(ei, ne, mode);

    // CSR build
    hist_kernel<<<nchunks, 256, 0, stream>>>(ei, ne, n, mode, btotal, K);
    scanK<<<1, 1024, 0, stream>>>(btotal, bbase, gcur, K);
    scatter_kernel<<<nchunks, 256, 0, stream>>>(ei, ne, n, mode, gcur, pairbuf, K);
    sort_kernel<<<K, 256, 0, stream>>>(pairbuf, bbase, rowptr, dis, col, n, K);
    gbounds_kernel<<<(n + 255) / 256, 256, 0, stream>>>(bt, mode, gstart, n, G);

    const int mm_grid = (n + MM_BM - 1) / MM_BM;
    const int sp_grid = (n + 3) / 4;

    mm_kernel<<<mm_grid, 256, 0, stream>>>(x, W1, dis, hsB, n);
    spmm_kernel<<<sp_grid, 256, 0, stream>>>(hsB, rowptr, col, dis, b1, hF, n, 1);
    mm_kernel<<<mm_grid, 256, 0, stream>>>(hF, W2, dis, hsB, n);
    spmm_kernel<<<sp_grid, 256, 0, stream>>>(hsB, rowptr, col, dis, b2, hF, n, 1);
    mm_kernel<<<mm_grid, 256, 0, stream>>>(hF, W3, dis, hsB, n);
    spmm_kernel<<<sp_grid, 256, 0, stream>>>(hsB, rowptr, col, dis, b3, hF, n, 0);

    poolhead_kernel<<<G, 256, 0, stream>>>(hF, gstart, Wl, bl, out, G);
}

// Round 6
// 337.529 us; speedup vs baseline: 2.4337x; 1.3284x over previous
//
#include <hip/hip_runtime.h>

#define NF 128            // feature dim
#define NFU 64            // uints per bf16 row (NF/2)
#define BW 128            // dst rows per bucket
#define KMAX 1024         // max buckets
#define CAP 3072          // max edges per bucket (mean 2048, sd 45)
#define CHUNK 8192        // edges per block in hist/scatter

typedef __attribute__((ext_vector_type(8))) short bf16x8;
typedef __attribute__((ext_vector_type(4))) float f32x4;
union U4S8 { uint4 u; bf16x8 s; };

// ---------------- integer-layout detection ----------------
__global__ void detect_kernel(const int* __restrict__ ei, int ne, int* __restrict__ mode) {
    if (threadIdx.x == 0 && blockIdx.x == 0) {
        int step = ne / 32; if (step < 1) step = 1;
        int all0 = 1;
        for (int k = 0; k < 16; ++k) {
            int idx = 2 * k * step + 1;
            if (ei[idx] != 0) { all0 = 0; break; }
        }
        *mode = all0;                            // 1 = int64 words, 0 = int32
    }
}

// ---------------- CSR build: hist -> prefix -> binned scatter -> bucket sort ----------------
__global__ __launch_bounds__(256) void hist_kernel(const int* __restrict__ ei, int ne, int n,
                                                   const int* __restrict__ mode, int* __restrict__ btotal,
                                                   int K) {
    __shared__ int hist[KMAX];
    int m = *mode;
    int tid = threadIdx.x;
    for (int k = tid; k < K; k += 256) hist[k] = 0;
    __syncthreads();
    int base = blockIdx.x * CHUNK;
    int end = min(base + CHUNK, ne);
    for (int e = base + tid; e < end; e += 256) {
        int dst = m ? ei[2 * (ne + e)] : ei[ne + e];
        if ((unsigned)dst < (unsigned)n) atomicAdd(&hist[dst >> 7], 1);
    }
    __syncthreads();
    for (int k = tid; k < K; k += 256)
        if (hist[k]) atomicAdd(&btotal[k], hist[k]);
}

__global__ __launch_bounds__(1024) void scanK(const int* __restrict__ btotal, int* __restrict__ bbase,
                                              int* __restrict__ gcur, int K) {
    __shared__ int sm[1024];
    int tid = threadIdx.x;
    int v = (tid < K) ? btotal[tid] : 0;
    sm[tid] = v;
    __syncthreads();
    for (int off = 1; off < 1024; off <<= 1) {
        int t = (tid >= off) ? sm[tid - off] : 0;
        __syncthreads();
        sm[tid] += t;
        __syncthreads();
    }
    if (tid < K) {
        int excl = sm[tid] - v;
        bbase[tid] = excl;
        gcur[tid] = excl;
        if (tid == K - 1) bbase[K] = sm[tid];
    }
}

__global__ __launch_bounds__(256) void scatter_kernel(const int* __restrict__ ei, int ne, int n,
                                                      const int* __restrict__ mode, int* __restrict__ gcur,
                                                      uint2* __restrict__ pairbuf, int K) {
    __shared__ int cur[KMAX];
    int m = *mode;
    int tid = threadIdx.x;
    for (int k = tid; k < K; k += 256) cur[k] = 0;
    __syncthreads();
    int base = blockIdx.x * CHUNK;
    int end = min(base + CHUNK, ne);
    for (int e = base + tid; e < end; e += 256) {
        int dst = m ? ei[2 * (ne + e)] : ei[ne + e];
        if ((unsigned)dst < (unsigned)n) atomicAdd(&cur[dst >> 7], 1);
    }
    __syncthreads();
    for (int k = tid; k < K; k += 256) {
        int c = cur[k];
        cur[k] = c ? atomicAdd(&gcur[k], c) : 0;
    }
    __syncthreads();
    for (int e = base + tid; e < end; e += 256) {
        int src = m ? ei[2 * e] : ei[e];
        int dst = m ? ei[2 * (ne + e)] : ei[ne + e];
        if ((unsigned)dst >= (unsigned)n || (unsigned)src >= (unsigned)n) continue;
        int pos = atomicAdd(&cur[dst >> 7], 1);
        pairbuf[pos] = make_uint2((unsigned)src, (unsigned)dst);
    }
}

__global__ __launch_bounds__(256) void sort_kernel(const uint2* __restrict__ pairbuf,
                                                   const int* __restrict__ bbase,
                                                   int* __restrict__ rowptr, float* __restrict__ dis,
                                                   int* __restrict__ col, int n, int K) {
    __shared__ uint2 spair[CAP];
    __shared__ int lcol[CAP];
    __shared__ int dcnt[BW];
    __shared__ int pref[BW];
    int tid = threadIdx.x;
    int b = blockIdx.x;
    int r0 = b * BW;
    int base = bbase[b];
    int end = bbase[b + 1];
    int cntb = end - base;
    if (cntb > CAP) cntb = CAP;

    for (int i = tid; i < cntb; i += 256) spair[i] = pairbuf[base + i];
    if (tid < BW) dcnt[tid] = 0;
    __syncthreads();
    for (int i = tid; i < cntb; i += 256) atomicAdd(&dcnt[spair[i].y & (BW - 1)], 1);
    __syncthreads();
    if (tid < BW) pref[tid] = dcnt[tid];
    __syncthreads();
    for (int off = 1; off < BW; off <<= 1) {
        int t = (tid < BW && tid >= off) ? pref[tid - off] : 0;
        __syncthreads();
        if (tid < BW) pref[tid] += t;
        __syncthreads();
    }
    if (tid < BW) {
        int d = r0 + tid;
        if (d < n) {
            int excl = pref[tid] - dcnt[tid];
            rowptr[d] = base + excl;
            dis[d] = rsqrtf((float)(dcnt[tid] + 1));
        }
    }
    if (b == K - 1 && tid == 0) rowptr[n] = end;
    if (tid < BW) dcnt[tid] = pref[tid] - dcnt[tid];
    __syncthreads();
    for (int i = tid; i < cntb; i += 256) {
        int slot = atomicAdd(&dcnt[spair[i].y & (BW - 1)], 1);
        if (slot < CAP) lcol[slot] = (int)spair[i].x;
    }
    __syncthreads();
    for (int i = tid; i < cntb; i += 256) col[base + i] = lcol[i];
}

// ---------------- bf16 helpers ----------------
__device__ inline unsigned pack_bf16(float a, float b) {
    unsigned ua = __float_as_uint(a), ub = __float_as_uint(b);
    ua = (ua + 0x7fffu + ((ua >> 16) & 1u)) >> 16;
    ub = (ub + 0x7fffu + ((ub >> 16) & 1u)) >> 16;
    return ua | (ub << 16);
}
__device__ inline float bflo(unsigned u) { return __uint_as_float(u << 16); }
__device__ inline float bfhi(unsigned u) { return __uint_as_float(u & 0xFFFF0000u); }

// ---------------- W pre-pack into MFMA "A-operand" fragments ----------------
// Wb[(jt*4+kb)*64 + lane] = 8 bf16: W[kb*32 + (lane>>4)*8 + jj][jt*16 + (lane&15)], jj=0..7
__global__ __launch_bounds__(256) void wprep_kernel(const float* __restrict__ W, uint4* __restrict__ Wb) {
    int tid = threadIdx.x;
#pragma unroll
    for (int it = 0; it < 8; ++it) {
        int item = it * 256 + tid;          // 0..2047
        int lane = item & 63;
        int kbjt = item >> 6;               // jt*4 + kb
        int kb = kbjt & 3, jt = kbjt >> 2;
        int k0 = kb * 32 + (lane >> 4) * 8;
        int j = jt * 16 + (lane & 15);
        unsigned p[4];
#pragma unroll
        for (int q = 0; q < 4; ++q)
            p[q] = pack_bf16(W[(size_t)(k0 + 2 * q) * NF + j], W[(size_t)(k0 + 2 * q + 1) * NF + j]);
        Wb[item] = make_uint4(p[0], p[1], p[2], p[3]);
    }
}

// ---------------- MFMA GEMM: hs[i] = bf16( (A[i] @ W) * dis[i] ) ----------------
// One wave = 16 rows x 128 cols. Operand-swapped mfma(w, a): per lane the 4 C regs
// are 4 consecutive output cols of row r0+(lane&15). No LDS.
__global__ __launch_bounds__(256) void mm_mfma_kernel(const void* __restrict__ A, int a_fp32,
                                                      const uint4* __restrict__ Wb,
                                                      const float* __restrict__ dis,
                                                      unsigned* __restrict__ hs, int n) {
    int tid = threadIdx.x;
    int wave = tid >> 6, lane = tid & 63;
    int r0 = blockIdx.x * 64 + wave * 16;
    if (r0 >= n) return;
    int lrow = lane & 15, lk = lane >> 4;
    int arow = min(r0 + lrow, n - 1);

    f32x4 acc[8];
#pragma unroll
    for (int j = 0; j < 8; ++j) acc[j] = (f32x4){0.f, 0.f, 0.f, 0.f};

    U4S8 af[4];
    if (a_fp32) {
        const float* Af = (const float*)A;
#pragma unroll
        for (int kb = 0; kb < 4; ++kb) {
            const float* p = Af + (size_t)arow * NF + kb * 32 + lk * 8;
            float4 x0 = *(const float4*)p;
            float4 x1 = *(const float4*)(p + 4);
            af[kb].u = make_uint4(pack_bf16(x0.x, x0.y), pack_bf16(x0.z, x0.w),
                                  pack_bf16(x1.x, x1.y), pack_bf16(x1.z, x1.w));
        }
    } else {
        const unsigned* Ab = (const unsigned*)A;
#pragma unroll
        for (int kb = 0; kb < 4; ++kb)
            af[kb].u = *(const uint4*)(Ab + (size_t)arow * NFU + kb * 16 + lk * 4);
    }

#pragma unroll
    for (int kb = 0; kb < 4; ++kb) {
#pragma unroll
        for (int jt = 0; jt < 8; ++jt) {
            U4S8 wf;
            wf.u = Wb[(jt * 4 + kb) * 64 + lane];
            acc[jt] = __builtin_amdgcn_mfma_f32_16x16x32_bf16(wf.s, af[kb].s, acc[jt], 0, 0, 0);
        }
    }

    if (r0 + lrow < n) {
        float dv = dis[r0 + lrow];
        unsigned* orow = hs + (size_t)(r0 + lrow) * NFU;
#pragma unroll
        for (int jt = 0; jt < 8; ++jt) {
            unsigned p0 = pack_bf16(acc[jt][0] * dv, acc[jt][1] * dv);
            unsigned p1 = pack_bf16(acc[jt][2] * dv, acc[jt][3] * dv);
            *(uint2*)(orow + jt * 8 + lk * 2) = make_uint2(p0, p1);
        }
    }
}

// ---------------- SpMM: one wave per dst row; 4 neighbor-groups x 16 lanes x uint4 ----------------
// out (bf16) = act( dis[i] * (sum_{e:dst=i} hs[col_e] + hs[i]) + b )
__global__ __launch_bounds__(256) void spmm_kernel(const unsigned* __restrict__ hs, const int* __restrict__ rowptr,
                                                   const int* __restrict__ col, const float* __restrict__ dis,
                                                   const float* __restrict__ b, unsigned* __restrict__ outb,
                                                   int n, int do_relu) {
    int wid = (blockIdx.x * blockDim.x + threadIdx.x) >> 6;
    int lane = threadIdx.x & 63;
    if (wid >= n) return;
    int s = rowptr[wid], e = rowptr[wid + 1];
    int deg = e - s;
    int group = lane >> 4, fl = lane & 15;

    float acc[8];
    if (group == 0) {   // self-loop counted once
        uint4 sv = *(const uint4*)(hs + (size_t)wid * NFU + fl * 4);
        acc[0] = bflo(sv.x); acc[1] = bfhi(sv.x);
        acc[2] = bflo(sv.y); acc[3] = bfhi(sv.y);
        acc[4] = bflo(sv.z); acc[5] = bfhi(sv.z);
        acc[6] = bflo(sv.w); acc[7] = bfhi(sv.w);
    } else {
#pragma unroll
        for (int k = 0; k < 8; ++k) acc[k] = 0.f;
    }

    int m64 = min(deg, 64);
    int cidx = (lane < m64) ? col[s + lane] : 0;

    for (int j0 = 0; j0 < m64; j0 += 4) {
        int c = __shfl(cidx, j0 + group);
        if (j0 + group < m64) {
            uint4 v = *(const uint4*)(hs + (size_t)c * NFU + fl * 4);
            acc[0] += bflo(v.x); acc[1] += bfhi(v.x);
            acc[2] += bflo(v.y); acc[3] += bfhi(v.y);
            acc[4] += bflo(v.z); acc[5] += bfhi(v.z);
            acc[6] += bflo(v.w); acc[7] += bfhi(v.w);
        }
    }
    for (int i = s + 64 + group; i < e; i += 4) {
        int c = col[i];
        uint4 v = *(const uint4*)(hs + (size_t)c * NFU + fl * 4);
        acc[0] += bflo(v.x); acc[1] += bfhi(v.x);
        acc[2] += bflo(v.y); acc[3] += bfhi(v.y);
        acc[4] += bflo(v.z); acc[5] += bfhi(v.z);
        acc[6] += bflo(v.w); acc[7] += bfhi(v.w);
    }

#pragma unroll
    for (int k = 0; k < 8; ++k) {
        acc[k] += __shfl_xor(acc[k], 16);
        acc[k] += __shfl_xor(acc[k], 32);
    }

    if (lane < 16) {
        float d = dis[wid];
        float4 bb0 = *(const float4*)(b + fl * 8);
        float4 bb1 = *(const float4*)(b + fl * 8 + 4);
        float o[8];
        o[0] = fmaf(d, acc[0], bb0.x); o[1] = fmaf(d, acc[1], bb0.y);
        o[2] = fmaf(d, acc[2], bb0.z); o[3] = fmaf(d, acc[3], bb0.w);
        o[4] = fmaf(d, acc[4], bb1.x); o[5] = fmaf(d, acc[5], bb1.y);
        o[6] = fmaf(d, acc[6], bb1.z); o[7] = fmaf(d, acc[7], bb1.w);
        if (do_relu) {
#pragma unroll
            for (int k = 0; k < 8; ++k) o[k] = fmaxf(o[k], 0.f);
        }
        unsigned q0 = pack_bf16(o[0], o[1]);
        unsigned q1 = pack_bf16(o[2], o[3]);
        unsigned q2 = pack_bf16(o[4], o[5]);
        unsigned q3 = pack_bf16(o[6], o[7]);
        *(uint4*)(outb + (size_t)wid * NFU + fl * 4) = make_uint4(q0, q1, q2, q3);
    }
}

// ---------------- graph boundaries from sorted batch ----------------
__global__ void gbounds_kernel(const int* __restrict__ batch, const int* __restrict__ mode,
                               int* __restrict__ gstart, int n, int G) {
    int m = *mode;
    int i = blockIdx.x * blockDim.x + threadIdx.x;
    if (i >= n) return;
    int g1 = m ? batch[2 * i] : batch[i];
    int g2 = (i == n - 1) ? G : (m ? batch[2 * (i + 1)] : batch[i + 1]);
    if ((unsigned)g1 > (unsigned)G) g1 = G;
    if ((unsigned)g2 > (unsigned)G) g2 = G;
    if (i == 0) for (int g = 0; g <= g1; ++g) gstart[g] = 0;
    for (int g = g1 + 1; g <= g2; ++g) gstart[g] = i + 1;
}

// ---------------- fused mean-pool + head (bf16 input) ----------------
__global__ __launch_bounds__(256) void poolhead_kernel(const unsigned* __restrict__ h, const int* __restrict__ gstart,
                                                       const float* __restrict__ Wl, const float* __restrict__ bl,
                                                       float* __restrict__ out, int G) {
    __shared__ float sacc[16][16][8];   // 8 KB
    int g = blockIdx.x;
    int s = gstart[g], e = gstart[g + 1];
    int tid = threadIdx.x;
    int rg = tid >> 4, fl = tid & 15;

    float acc[8] = {0.f, 0.f, 0.f, 0.f, 0.f, 0.f, 0.f, 0.f};
    for (int i = s + rg; i < e; i += 16) {
        uint4 v = *(const uint4*)(h + (size_t)i * NFU + fl * 4);
        acc[0] += bflo(v.x); acc[1] += bfhi(v.x);
        acc[2] += bflo(v.y); acc[3] += bfhi(v.y);
        acc[4] += bflo(v.z); acc[5] += bfhi(v.z);
        acc[6] += bflo(v.w); acc[7] += bfhi(v.w);
    }
#pragma unroll
    for (int k = 0; k < 8; ++k) sacc[rg][fl][k] = acc[k];
    __syncthreads();
    if (tid < 16) {
        float t[8] = {0.f, 0.f, 0.f, 0.f, 0.f, 0.f, 0.f, 0.f};
        for (int r = 0; r < 16; ++r)
#pragma unroll
            for (int k = 0; k < 8; ++k) t[k] += sacc[r][tid][k];
        float inv = 1.0f / fmaxf((float)(e - s), 1.0f);
        float o0 = 0.f, o1 = 0.f;
#pragma unroll
        for (int k = 0; k < 8; ++k) {
            int f = tid * 8 + k;
            o0 += t[k] * inv * Wl[f * 2];
            o1 += t[k] * inv * Wl[f * 2 + 1];
        }
#pragma unroll
        for (int off2 = 8; off2; off2 >>= 1) {
            o0 += __shfl_down(o0, off2, 16);
            o1 += __shfl_down(o1, off2, 16);
        }
        if (tid == 0) {
            out[g * 2 + 0] = o0 + bl[0];
            out[g * 2 + 1] = o1 + bl[1];
        }
    }
}

extern "C" void kernel_launch(void* const* d_in, const int* in_sizes, int n_in,
                              void* d_out, int out_size, void* d_ws, size_t ws_size,
                              hipStream_t stream) {
    const float* x  = (const float*)d_in[0];
    const int*   ei = (const int*)d_in[1];
    const int*   bt = (const int*)d_in[2];
    const float* W1 = (const float*)d_in[3];
    const float* b1 = (const float*)d_in[4];
    const float* W2 = (const float*)d_in[5];
    const float* b2 = (const float*)d_in[6];
    const float* W3 = (const float*)d_in[7];
    const float* b3 = (const float*)d_in[8];
    const float* Wl = (const float*)d_in[9];
    const float* bl = (const float*)d_in[10];
    float* out = (float*)d_out;

    const int n  = in_sizes[2];        // 100000 nodes
    const int ne = in_sizes[1] / 2;    // 1600000 edges
    const int G  = out_size / 2;       // 512 graphs
    const int K  = (n + BW - 1) / BW;  // 782 buckets

    size_t off = 0;
    auto alloc = [&](size_t bytes) { size_t o = off; off += (bytes + 255) & ~(size_t)255; return o; };
    char* ws = (char*)d_ws;
    unsigned* hB     = (unsigned*)(ws + alloc((size_t)n * NFU * 4));  // bf16 node features
    unsigned* hsB    = (unsigned*)(ws + alloc((size_t)n * NFU * 4));  // bf16 h@W * dis
    uint2*    pairbuf= (uint2*)   (ws + alloc((size_t)ne * 8));
    int*      col    = (int*)     (ws + alloc((size_t)ne * 4));
    int*      rowptr = (int*)     (ws + alloc((size_t)(n + 1) * 4));
    float*    dis    = (float*)   (ws + alloc((size_t)n * 4));
    int*      btotal = (int*)     (ws + alloc((size_t)(K + 1) * 4));
    int*      bbase  = (int*)     (ws + alloc((size_t)(K + 1) * 4));
    int*      gcur   = (int*)     (ws + alloc((size_t)(K + 1) * 4));
    int*      gstart = (int*)     (ws + alloc((size_t)(G + 1) * 4));
    uint4*    Wb1    = (uint4*)   (ws + alloc(2048 * 16));
    uint4*    Wb2    = (uint4*)   (ws + alloc(2048 * 16));
    uint4*    Wb3    = (uint4*)   (ws + alloc(2048 * 16));
    int*      mode   = (int*)     (ws + alloc(256));
    (void)ws_size;

    const int nchunks = (ne + CHUNK - 1) / CHUNK;

    hipMemsetAsync(btotal, 0, (size_t)(K + 1) * 4, stream);

    detect_kernel<<<1, 64, 0, stream>>>(ei, ne, mode);

    // weight pre-pack (tiny, L2-resident afterwards)
    wprep_kernel<<<1, 256, 0, stream>>>(W1, Wb1);
    wprep_kernel<<<1, 256, 0, stream>>>(W2, Wb2);
    wprep_kernel<<<1, 256, 0, stream>>>(W3, Wb3);

    // CSR build
    hist_kernel<<<nchunks, 256, 0, stream>>>(ei, ne, n, mode, btotal, K);
    scanK<<<1, 1024, 0, stream>>>(btotal, bbase, gcur, K);
    scatter_kernel<<<nchunks, 256, 0, stream>>>(ei, ne, n, mode, gcur, pairbuf, K);
    sort_kernel<<<K, 256, 0, stream>>>(pairbuf, bbase, rowptr, dis, col, n, K);
    gbounds_kernel<<<(n + 255) / 256, 256, 0, stream>>>(bt, mode, gstart, n, G);

    const int mm_grid = (n + 63) / 64;
    const int sp_grid = (n + 3) / 4;

    mm_mfma_kernel<<<mm_grid, 256, 0, stream>>>(x, 1, Wb1, dis, hsB, n);
    spmm_kernel<<<sp_grid, 256, 0, stream>>>(hsB, rowptr, col, dis, b1, hB, n, 1);
    mm_mfma_kernel<<<mm_grid, 256, 0, stream>>>(hB, 0, Wb2, dis, hsB, n);
    spmm_kernel<<<sp_grid, 256, 0, stream>>>(hsB, rowptr, col, dis, b2, hB, n, 1);
    mm_mfma_kernel<<<mm_grid, 256, 0, stream>>>(hB, 0, Wb3, dis, hsB, n);
    spmm_kernel<<<sp_grid, 256, 0, stream>>>(hsB, rowptr, col, dis, b3, hB, n, 0);

    poolhead_kernel<<<G, 256, 0, stream>>>(hB, gstart, Wl, bl, out, G);
}

// Round 7
// 321.264 us; speedup vs baseline: 2.5569x; 1.0506x over previous
//
#include <hip/hip_runtime.h>

#define NF 128            // feature dim
#define NFU 64            // uints per bf16 row (NF/2)
#define BW 128            // dst rows per bucket
#define KMAX 1024         // max buckets
#define CAP 3072          // max edges per bucket (mean 2048, sd 45)
#define CHUNK 8192        // edges per block in hist/scatter

typedef __attribute__((ext_vector_type(8))) short bf16x8;
typedef __attribute__((ext_vector_type(4))) float f32x4;
typedef __attribute__((ext_vector_type(2))) float f32x2;
union U4S8 { uint4 u; bf16x8 s; };

// ---------------- integer-layout detection ----------------
__global__ void detect_kernel(const int* __restrict__ ei, int ne, int* __restrict__ mode) {
    if (threadIdx.x == 0 && blockIdx.x == 0) {
        int step = ne / 32; if (step < 1) step = 1;
        int all0 = 1;
        for (int k = 0; k < 16; ++k) {
            int idx = 2 * k * step + 1;
            if (ei[idx] != 0) { all0 = 0; break; }
        }
        *mode = all0;                            // 1 = int64 words, 0 = int32
    }
}

// ---------------- pass 1a: per-bucket edge counts (+ per-block counts saved) ----------------
__global__ __launch_bounds__(256) void hist_kernel(const int* __restrict__ ei, int ne, int n,
                                                   const int* __restrict__ mode, int* __restrict__ btotal,
                                                   int* __restrict__ blkcnt, int K) {
    __shared__ int hist[KMAX];
    int m = *mode;
    int tid = threadIdx.x;
    for (int k = tid; k < K; k += 256) hist[k] = 0;
    __syncthreads();
    int base = blockIdx.x * CHUNK;
    int end = min(base + CHUNK, ne);
    for (int e = base + tid; e < end; e += 256) {
        int dst = m ? ei[2 * (ne + e)] : ei[ne + e];
        if ((unsigned)dst < (unsigned)n) atomicAdd(&hist[dst >> 7], 1);
    }
    __syncthreads();
    for (int k = tid; k < K; k += 256) {
        int c = hist[k];
        blkcnt[(size_t)blockIdx.x * K + k] = c;
        if (c) atomicAdd(&btotal[k], c);
    }
}

// ---------------- pass 1b: prefix over bucket totals ----------------
__global__ __launch_bounds__(1024) void scanK(const int* __restrict__ btotal, int* __restrict__ bbase,
                                              int* __restrict__ gcur, int K) {
    __shared__ int sm[1024];
    int tid = threadIdx.x;
    int v = (tid < K) ? btotal[tid] : 0;
    sm[tid] = v;
    __syncthreads();
    for (int off = 1; off < 1024; off <<= 1) {
        int t = (tid >= off) ? sm[tid - off] : 0;
        __syncthreads();
        sm[tid] += t;
        __syncthreads();
    }
    if (tid < K) {
        int excl = sm[tid] - v;
        bbase[tid] = excl;
        gcur[tid] = excl;
        if (tid == K - 1) bbase[K] = sm[tid];
    }
}

// ---------------- pass 1c: single-pass bucketed scatter (reserve from saved counts) ----------------
__global__ __launch_bounds__(256) void scatter_kernel(const int* __restrict__ ei, int ne, int n,
                                                      const int* __restrict__ mode, const int* __restrict__ blkcnt,
                                                      int* __restrict__ gcur, unsigned* __restrict__ pairbuf,
                                                      int K) {
    __shared__ int cur[KMAX];
    int m = *mode;
    int tid = threadIdx.x;
    for (int k = tid; k < K; k += 256) {
        int c = blkcnt[(size_t)blockIdx.x * K + k];
        cur[k] = c ? atomicAdd(&gcur[k], c) : 0;
    }
    __syncthreads();
    int base = blockIdx.x * CHUNK;
    int end = min(base + CHUNK, ne);
    for (int e = base + tid; e < end; e += 256) {
        int src = m ? ei[2 * e] : ei[e];
        int dst = m ? ei[2 * (ne + e)] : ei[ne + e];
        if ((unsigned)dst >= (unsigned)n || (unsigned)src >= (unsigned)n) continue;
        int pos = atomicAdd(&cur[dst >> 7], 1);
        pairbuf[pos] = (unsigned)src | ((unsigned)(dst & (BW - 1)) << 24);   // n < 2^24
    }
}

// ---------------- pass 2: per-bucket counting sort + degree/rowptr/dis ----------------
__global__ __launch_bounds__(256) void sort_kernel(const unsigned* __restrict__ pairbuf,
                                                   const int* __restrict__ bbase,
                                                   int* __restrict__ rowptr, float* __restrict__ dis,
                                                   int* __restrict__ col, int n, int K) {
    __shared__ unsigned spair[CAP];   // 12 KB
    __shared__ int lcol[CAP];         // 12 KB
    __shared__ int dcnt[BW];
    __shared__ int pref[BW];
    int tid = threadIdx.x;
    int b = blockIdx.x;
    int r0 = b * BW;
    int base = bbase[b];
    int end = bbase[b + 1];
    int cntb = end - base;
    if (cntb > CAP) cntb = CAP;

    for (int i = tid; i < cntb; i += 256) spair[i] = pairbuf[base + i];
    if (tid < BW) dcnt[tid] = 0;
    __syncthreads();
    for (int i = tid; i < cntb; i += 256) atomicAdd(&dcnt[spair[i] >> 24], 1);
    __syncthreads();
    if (tid < BW) pref[tid] = dcnt[tid];
    __syncthreads();
    for (int off = 1; off < BW; off <<= 1) {
        int t = (tid < BW && tid >= off) ? pref[tid - off] : 0;
        __syncthreads();
        if (tid < BW) pref[tid] += t;
        __syncthreads();
    }
    if (tid < BW) {
        int d = r0 + tid;
        if (d < n) {
            int excl = pref[tid] - dcnt[tid];
            rowptr[d] = base + excl;
            dis[d] = rsqrtf((float)(dcnt[tid] + 1));
        }
    }
    if (b == K - 1 && tid == 0) rowptr[n] = end;
    if (tid < BW) dcnt[tid] = pref[tid] - dcnt[tid];
    __syncthreads();
    for (int i = tid; i < cntb; i += 256) {
        unsigned p = spair[i];
        int slot = atomicAdd(&dcnt[p >> 24], 1);
        if (slot < CAP) lcol[slot] = (int)(p & 0xFFFFFFu);
    }
    __syncthreads();
    for (int i = tid; i < cntb; i += 256) col[base + i] = lcol[i];
}

// ---------------- bf16 helpers ----------------
__device__ inline unsigned pack_bf16(float a, float b) {
    unsigned ua = __float_as_uint(a), ub = __float_as_uint(b);
    ua = (ua + 0x7fffu + ((ua >> 16) & 1u)) >> 16;
    ub = (ub + 0x7fffu + ((ub >> 16) & 1u)) >> 16;
    return ua | (ub << 16);
}
__device__ inline float bflo(unsigned u) { return __uint_as_float(u << 16); }
__device__ inline float bfhi(unsigned u) { return __uint_as_float(u & 0xFFFF0000u); }

// ---------------- W pre-pack (3 weights, one launch) ----------------
// Wb[(jt*4+kb)*64 + lane] = 8 bf16: W[kb*32 + (lane>>4)*8 + jj][jt*16 + (lane&15)]
__global__ __launch_bounds__(256) void wprep3_kernel(const float* __restrict__ W1, const float* __restrict__ W2,
                                                     const float* __restrict__ W3, uint4* __restrict__ Wb) {
    const float* W = (blockIdx.x == 0) ? W1 : (blockIdx.x == 1) ? W2 : W3;
    uint4* o = Wb + (size_t)blockIdx.x * 2048;
    int tid = threadIdx.x;
#pragma unroll
    for (int it = 0; it < 8; ++it) {
        int item = it * 256 + tid;          // 0..2047
        int lane = item & 63;
        int kbjt = item >> 6;               // jt*4 + kb
        int kb = kbjt & 3, jt = kbjt >> 2;
        int k0 = kb * 32 + (lane >> 4) * 8;
        int j = jt * 16 + (lane & 15);
        unsigned p[4];
#pragma unroll
        for (int q = 0; q < 4; ++q)
            p[q] = pack_bf16(W[(size_t)(k0 + 2 * q) * NF + j], W[(size_t)(k0 + 2 * q + 1) * NF + j]);
        o[item] = make_uint4(p[0], p[1], p[2], p[3]);
    }
}

// ---------------- MFMA GEMM: hs[i] = bf16( (A[i] @ W) * dis[i] ) ----------------
__global__ __launch_bounds__(256) void mm_mfma_kernel(const void* __restrict__ A, int a_fp32,
                                                      const uint4* __restrict__ Wb,
                                                      const float* __restrict__ dis,
                                                      unsigned* __restrict__ hs, int n) {
    int tid = threadIdx.x;
    int wave = tid >> 6, lane = tid & 63;
    int r0 = blockIdx.x * 64 + wave * 16;
    if (r0 >= n) return;
    int lrow = lane & 15, lk = lane >> 4;
    int arow = min(r0 + lrow, n - 1);

    f32x4 acc[8];
#pragma unroll
    for (int j = 0; j < 8; ++j) acc[j] = (f32x4){0.f, 0.f, 0.f, 0.f};

    U4S8 af[4];
    if (a_fp32) {
        const float* Af = (const float*)A;
#pragma unroll
        for (int kb = 0; kb < 4; ++kb) {
            const float* p = Af + (size_t)arow * NF + kb * 32 + lk * 8;
            float4 x0 = *(const float4*)p;
            float4 x1 = *(const float4*)(p + 4);
            af[kb].u = make_uint4(pack_bf16(x0.x, x0.y), pack_bf16(x0.z, x0.w),
                                  pack_bf16(x1.x, x1.y), pack_bf16(x1.z, x1.w));
        }
    } else {
        const unsigned* Ab = (const unsigned*)A;
#pragma unroll
        for (int kb = 0; kb < 4; ++kb)
            af[kb].u = *(const uint4*)(Ab + (size_t)arow * NFU + kb * 16 + lk * 4);
    }

#pragma unroll
    for (int kb = 0; kb < 4; ++kb) {
#pragma unroll
        for (int jt = 0; jt < 8; ++jt) {
            U4S8 wf;
            wf.u = Wb[(jt * 4 + kb) * 64 + lane];
            acc[jt] = __builtin_amdgcn_mfma_f32_16x16x32_bf16(wf.s, af[kb].s, acc[jt], 0, 0, 0);
        }
    }

    if (r0 + lrow < n) {
        float dv = dis[r0 + lrow];
        unsigned* orow = hs + (size_t)(r0 + lrow) * NFU;
#pragma unroll
        for (int jt = 0; jt < 8; ++jt) {
            unsigned p0 = pack_bf16(acc[jt][0] * dv, acc[jt][1] * dv);
            unsigned p1 = pack_bf16(acc[jt][2] * dv, acc[jt][3] * dv);
            *(uint2*)(orow + jt * 8 + lk * 2) = make_uint2(p0, p1);
        }
    }
}

// ---------------- SpMM: one wave per dst row; 4 groups x 16 lanes x uint4; staged loads ----------------
#define SPACC(v)                                              \
    { a0 += (f32x2){bflo((v).x), bfhi((v).x)};                \
      a1 += (f32x2){bflo((v).y), bfhi((v).y)};                \
      a2 += (f32x2){bflo((v).z), bfhi((v).z)};                \
      a3 += (f32x2){bflo((v).w), bfhi((v).w)}; }

__global__ __launch_bounds__(256) void spmm_kernel(const unsigned* __restrict__ hs, const int* __restrict__ rowptr,
                                                   const int* __restrict__ col, const float* __restrict__ dis,
                                                   const float* __restrict__ b, unsigned* __restrict__ outb,
                                                   int n, int do_relu) {
    int wid = (blockIdx.x * blockDim.x + threadIdx.x) >> 6;
    int lane = threadIdx.x & 63;
    if (wid >= n) return;
    int s = rowptr[wid], e = rowptr[wid + 1];
    int deg = e - s;
    int group = lane >> 4, fl = lane & 15;

    f32x2 a0 = {0.f, 0.f}, a1 = {0.f, 0.f}, a2 = {0.f, 0.f}, a3 = {0.f, 0.f};
    if (group == 0) {   // self-loop counted once
        uint4 sv = *(const uint4*)(hs + (size_t)wid * NFU + fl * 4);
        SPACC(sv);
    }

    int m64 = min(deg, 64);
    int cidx = (lane < m64) ? col[s + lane] : 0;

    int j0 = 0;
    for (; j0 + 8 <= m64; j0 += 8) {       // 2 gather loads in flight
        int ca = __shfl(cidx, j0 + group);
        int cb = __shfl(cidx, j0 + 4 + group);
        uint4 va = *(const uint4*)(hs + (size_t)ca * NFU + fl * 4);
        uint4 vb = *(const uint4*)(hs + (size_t)cb * NFU + fl * 4);
        SPACC(va);
        SPACC(vb);
    }
    for (; j0 < m64; j0 += 4) {
        int jj = j0 + group;
        int c = __shfl(cidx, jj);
        if (jj < m64) {
            uint4 v = *(const uint4*)(hs + (size_t)c * NFU + fl * 4);
            SPACC(v);
        }
    }
    for (int i = s + 64 + group; i < e; i += 4) {   // rare tail: deg > 64
        int c = col[i];
        uint4 v = *(const uint4*)(hs + (size_t)c * NFU + fl * 4);
        SPACC(v);
    }

#pragma unroll
    for (int k = 0; k < 2; ++k) {
        a0[k] += __shfl_xor(a0[k], 16); a0[k] += __shfl_xor(a0[k], 32);
        a1[k] += __shfl_xor(a1[k], 16); a1[k] += __shfl_xor(a1[k], 32);
        a2[k] += __shfl_xor(a2[k], 16); a2[k] += __shfl_xor(a2[k], 32);
        a3[k] += __shfl_xor(a3[k], 16); a3[k] += __shfl_xor(a3[k], 32);
    }

    if (lane < 16) {
        float d = dis[wid];
        float4 bb0 = *(const float4*)(b + fl * 8);
        float4 bb1 = *(const float4*)(b + fl * 8 + 4);
        float o[8];
        o[0] = fmaf(d, a0[0], bb0.x); o[1] = fmaf(d, a0[1], bb0.y);
        o[2] = fmaf(d, a1[0], bb0.z); o[3] = fmaf(d, a1[1], bb0.w);
        o[4] = fmaf(d, a2[0], bb1.x); o[5] = fmaf(d, a2[1], bb1.y);
        o[6] = fmaf(d, a3[0], bb1.z); o[7] = fmaf(d, a3[1], bb1.w);
        if (do_relu) {
#pragma unroll
            for (int k = 0; k < 8; ++k) o[k] = fmaxf(o[k], 0.f);
        }
        unsigned q0 = pack_bf16(o[0], o[1]);
        unsigned q1 = pack_bf16(o[2], o[3]);
        unsigned q2 = pack_bf16(o[4], o[5]);
        unsigned q3 = pack_bf16(o[6], o[7]);
        *(uint4*)(outb + (size_t)wid * NFU + fl * 4) = make_uint4(q0, q1, q2, q3);
    }
}

// ---------------- graph boundaries from sorted batch ----------------
__global__ void gbounds_kernel(const int* __restrict__ batch, const int* __restrict__ mode,
                               int* __restrict__ gstart, int n, int G) {
    int m = *mode;
    int i = blockIdx.x * blockDim.x + threadIdx.x;
    if (i >= n) return;
    int g1 = m ? batch[2 * i] : batch[i];
    int g2 = (i == n - 1) ? G : (m ? batch[2 * (i + 1)] : batch[i + 1]);
    if ((unsigned)g1 > (unsigned)G) g1 = G;
    if ((unsigned)g2 > (unsigned)G) g2 = G;
    if (i == 0) for (int g = 0; g <= g1; ++g) gstart[g] = 0;
    for (int g = g1 + 1; g <= g2; ++g) gstart[g] = i + 1;
}

// ---------------- fused mean-pool + head: 4 blocks per graph, atomic partials ----------------
__global__ __launch_bounds__(256) void poolhead_kernel(const unsigned* __restrict__ h, const int* __restrict__ gstart,
                                                       const float* __restrict__ Wl, const float* __restrict__ bl,
                                                       float* __restrict__ out, int G) {
    __shared__ float sacc[16][16][8];   // 8 KB
    int g = blockIdx.x >> 2, sub = blockIdx.x & 3;
    int s0 = gstart[g], e0 = gstart[g + 1];
    int cnt = e0 - s0;
    int per = (cnt + 3) >> 2;
    int s = s0 + sub * per;
    int e = min(s + per, e0);
    int tid = threadIdx.x;
    int rg = tid >> 4, fl = tid & 15;

    float acc[8] = {0.f, 0.f, 0.f, 0.f, 0.f, 0.f, 0.f, 0.f};
    for (int i = s + rg; i < e; i += 16) {
        uint4 v = *(const uint4*)(h + (size_t)i * NFU + fl * 4);
        acc[0] += bflo(v.x); acc[1] += bfhi(v.x);
        acc[2] += bflo(v.y); acc[3] += bfhi(v.y);
        acc[4] += bflo(v.z); acc[5] += bfhi(v.z);
        acc[6] += bflo(v.w); acc[7] += bfhi(v.w);
    }
#pragma unroll
    for (int k = 0; k < 8; ++k) sacc[rg][fl][k] = acc[k];
    __syncthreads();
    if (tid < 16) {
        float t[8] = {0.f, 0.f, 0.f, 0.f, 0.f, 0.f, 0.f, 0.f};
        for (int r = 0; r < 16; ++r)
#pragma unroll
            for (int k = 0; k < 8; ++k) t[k] += sacc[r][tid][k];
        float inv = 1.0f / fmaxf((float)cnt, 1.0f);
        float o0 = 0.f, o1 = 0.f;
#pragma unroll
        for (int k = 0; k < 8; ++k) {
            int f = tid * 8 + k;
            o0 += t[k] * inv * Wl[f * 2];
            o1 += t[k] * inv * Wl[f * 2 + 1];
        }
#pragma unroll
        for (int off2 = 8; off2; off2 >>= 1) {
            o0 += __shfl_down(o0, off2, 16);
            o1 += __shfl_down(o1, off2, 16);
        }
        if (tid == 0) {
            if (sub == 0) { o0 += bl[0]; o1 += bl[1]; }
            atomicAdd(&out[g * 2 + 0], o0);
            atomicAdd(&out[g * 2 + 1], o1);
        }
    }
}

extern "C" void kernel_launch(void* const* d_in, const int* in_sizes, int n_in,
                              void* d_out, int out_size, void* d_ws, size_t ws_size,
                              hipStream_t stream) {
    const float* x  = (const float*)d_in[0];
    const int*   ei = (const int*)d_in[1];
    const int*   bt = (const int*)d_in[2];
    const float* W1 = (const float*)d_in[3];
    const float* b1 = (const float*)d_in[4];
    const float* W2 = (const float*)d_in[5];
    const float* b2 = (const float*)d_in[6];
    const float* W3 = (const float*)d_in[7];
    const float* b3 = (const float*)d_in[8];
    const float* Wl = (const float*)d_in[9];
    const float* bl = (const float*)d_in[10];
    float* out = (float*)d_out;

    const int n  = in_sizes[2];        // 100000 nodes
    const int ne = in_sizes[1] / 2;    // 1600000 edges
    const int G  = out_size / 2;       // 512 graphs
    const int K  = (n + BW - 1) / BW;  // 782 buckets
    const int nchunks = (ne + CHUNK - 1) / CHUNK;

    size_t off = 0;
    auto alloc = [&](size_t bytes) { size_t o = off; off += (bytes + 255) & ~(size_t)255; return o; };
    char* ws = (char*)d_ws;
    unsigned* hB     = (unsigned*)(ws + alloc((size_t)n * NFU * 4));  // bf16 node features
    unsigned* hsB    = (unsigned*)(ws + alloc((size_t)n * NFU * 4));  // bf16 h@W * dis
    unsigned* pairbuf= (unsigned*)(ws + alloc((size_t)ne * 4));
    int*      col    = (int*)     (ws + alloc((size_t)ne * 4));
    int*      rowptr = (int*)     (ws + alloc((size_t)(n + 1) * 4));
    float*    dis    = (float*)   (ws + alloc((size_t)n * 4));
    int*      btotal = (int*)     (ws + alloc((size_t)(K + 1) * 4));
    int*      bbase  = (int*)     (ws + alloc((size_t)(K + 1) * 4));
    int*      gcur   = (int*)     (ws + alloc((size_t)(K + 1) * 4));
    int*      gstart = (int*)     (ws + alloc((size_t)(G + 1) * 4));
    int*      blkcnt = (int*)     (ws + alloc((size_t)nchunks * K * 4));
    uint4*    Wb     = (uint4*)   (ws + alloc(3 * 2048 * 16));
    int*      mode   = (int*)     (ws + alloc(256));
    (void)ws_size;

    hipMemsetAsync(btotal, 0, (size_t)(K + 1) * 4, stream);
    hipMemsetAsync(out, 0, (size_t)out_size * 4, stream);

    detect_kernel<<<1, 64, 0, stream>>>(ei, ne, mode);
    wprep3_kernel<<<3, 256, 0, stream>>>(W1, W2, W3, Wb);

    // CSR build
    hist_kernel<<<nchunks, 256, 0, stream>>>(ei, ne, n, mode, btotal, blkcnt, K);
    scanK<<<1, 1024, 0, stream>>>(btotal, bbase, gcur, K);
    scatter_kernel<<<nchunks, 256, 0, stream>>>(ei, ne, n, mode, blkcnt, gcur, pairbuf, K);
    sort_kernel<<<K, 256, 0, stream>>>(pairbuf, bbase, rowptr, dis, col, n, K);
    gbounds_kernel<<<(n + 255) / 256, 256, 0, stream>>>(bt, mode, gstart, n, G);

    const int mm_grid = (n + 63) / 64;
    const int sp_grid = (n + 3) / 4;

    mm_mfma_kernel<<<mm_grid, 256, 0, stream>>>(x, 1, Wb, dis, hsB, n);
    spmm_kernel<<<sp_grid, 256, 0, stream>>>(hsB, rowptr, col, dis, b1, hB, n, 1);
    mm_mfma_kernel<<<mm_grid, 256, 0, stream>>>(hB, 0, Wb + 2048, dis, hsB, n);
    spmm_kernel<<<sp_grid, 256, 0, stream>>>(hsB, rowptr, col, dis, b2, hB, n, 1);
    mm_mfma_kernel<<<mm_grid, 256, 0, stream>>>(hB, 0, Wb + 4096, dis, hsB, n);
    spmm_kernel<<<sp_grid, 256, 0, stream>>>(hsB, rowptr, col, dis, b3, hB, n, 0);

    poolhead_kernel<<<G * 4, 256, 0, stream>>>(hB, gstart, Wl, bl, out, G);
}

// Round 8
// 320.780 us; speedup vs baseline: 2.5607x; 1.0015x over previous
//
#include <hip/hip_runtime.h>

#define NF 128            // feature dim
#define NFU 64            // uints per bf16 row (NF/2)
#define BW 128            // dst rows per bucket
#define KMAX 1024         // max buckets
#define CAP 3072          // max edges per bucket (mean 2048, sd 45)
#define CHUNK 8192        // edges per block in hist/scatter

typedef __attribute__((ext_vector_type(8))) short bf16x8;
typedef __attribute__((ext_vector_type(4))) float f32x4;
typedef __attribute__((ext_vector_type(2))) float f32x2;
union U4S8 { uint4 u; bf16x8 s; };

// ---------------- integer-layout detection ----------------
__global__ void detect_kernel(const int* __restrict__ ei, int ne, int* __restrict__ mode) {
    if (threadIdx.x == 0 && blockIdx.x == 0) {
        int step = ne / 32; if (step < 1) step = 1;
        int all0 = 1;
        for (int k = 0; k < 16; ++k) {
            int idx = 2 * k * step + 1;
            if (ei[idx] != 0) { all0 = 0; break; }
        }
        *mode = all0;                            // 1 = int64 words, 0 = int32
    }
}

// ---------------- pass 1a: per-bucket edge counts (+ per-block counts saved) ----------------
__global__ __launch_bounds__(256) void hist_kernel(const int* __restrict__ ei, int ne, int n,
                                                   const int* __restrict__ mode, int* __restrict__ btotal,
                                                   int* __restrict__ blkcnt, int K) {
    __shared__ int hist[KMAX];
    int m = *mode;
    int tid = threadIdx.x;
    for (int k = tid; k < K; k += 256) hist[k] = 0;
    __syncthreads();
    int base = blockIdx.x * CHUNK;
    int end = min(base + CHUNK, ne);
    for (int e = base + tid; e < end; e += 256) {
        int dst = m ? ei[2 * (ne + e)] : ei[ne + e];
        if ((unsigned)dst < (unsigned)n) atomicAdd(&hist[dst >> 7], 1);
    }
    __syncthreads();
    for (int k = tid; k < K; k += 256) {
        int c = hist[k];
        blkcnt[(size_t)blockIdx.x * K + k] = c;
        if (c) atomicAdd(&btotal[k], c);
    }
}

// ---------------- pass 1b: prefix over bucket totals ----------------
__global__ __launch_bounds__(1024) void scanK(const int* __restrict__ btotal, int* __restrict__ bbase,
                                              int* __restrict__ gcur, int K) {
    __shared__ int sm[1024];
    int tid = threadIdx.x;
    int v = (tid < K) ? btotal[tid] : 0;
    sm[tid] = v;
    __syncthreads();
    for (int off = 1; off < 1024; off <<= 1) {
        int t = (tid >= off) ? sm[tid - off] : 0;
        __syncthreads();
        sm[tid] += t;
        __syncthreads();
    }
    if (tid < K) {
        int excl = sm[tid] - v;
        bbase[tid] = excl;
        gcur[tid] = excl;
        if (tid == K - 1) bbase[K] = sm[tid];
    }
}

// ---------------- pass 1c: single-pass bucketed scatter (reserve from saved counts) ----------------
__global__ __launch_bounds__(256) void scatter_kernel(const int* __restrict__ ei, int ne, int n,
                                                      const int* __restrict__ mode, const int* __restrict__ blkcnt,
                                                      int* __restrict__ gcur, unsigned* __restrict__ pairbuf,
                                                      int K) {
    __shared__ int cur[KMAX];
    int m = *mode;
    int tid = threadIdx.x;
    for (int k = tid; k < K; k += 256) {
        int c = blkcnt[(size_t)blockIdx.x * K + k];
        cur[k] = c ? atomicAdd(&gcur[k], c) : 0;
    }
    __syncthreads();
    int base = blockIdx.x * CHUNK;
    int end = min(base + CHUNK, ne);
    for (int e = base + tid; e < end; e += 256) {
        int src = m ? ei[2 * e] : ei[e];
        int dst = m ? ei[2 * (ne + e)] : ei[ne + e];
        if ((unsigned)dst >= (unsigned)n || (unsigned)src >= (unsigned)n) continue;
        int pos = atomicAdd(&cur[dst >> 7], 1);
        pairbuf[pos] = (unsigned)src | ((unsigned)(dst & (BW - 1)) << 24);   // n < 2^24
    }
}

// ---------------- pass 2: per-bucket counting sort + degree/rowptr/dis ----------------
__global__ __launch_bounds__(256) void sort_kernel(const unsigned* __restrict__ pairbuf,
                                                   const int* __restrict__ bbase,
                                                   int* __restrict__ rowptr, float* __restrict__ dis,
                                                   int* __restrict__ col, int n, int K) {
    __shared__ unsigned spair[CAP];   // 12 KB
    __shared__ int lcol[CAP];         // 12 KB
    __shared__ int dcnt[BW];
    __shared__ int pref[BW];
    int tid = threadIdx.x;
    int b = blockIdx.x;
    int r0 = b * BW;
    int base = bbase[b];
    int end = bbase[b + 1];
    int cntb = end - base;
    if (cntb > CAP) cntb = CAP;

    for (int i = tid; i < cntb; i += 256) spair[i] = pairbuf[base + i];
    if (tid < BW) dcnt[tid] = 0;
    __syncthreads();
    for (int i = tid; i < cntb; i += 256) atomicAdd(&dcnt[spair[i] >> 24], 1);
    __syncthreads();
    if (tid < BW) pref[tid] = dcnt[tid];
    __syncthreads();
    for (int off = 1; off < BW; off <<= 1) {
        int t = (tid < BW && tid >= off) ? pref[tid - off] : 0;
        __syncthreads();
        if (tid < BW) pref[tid] += t;
        __syncthreads();
    }
    if (tid < BW) {
        int d = r0 + tid;
        if (d < n) {
            int excl = pref[tid] - dcnt[tid];
            rowptr[d] = base + excl;
            dis[d] = rsqrtf((float)(dcnt[tid] + 1));
        }
    }
    if (b == K - 1 && tid == 0) rowptr[n] = end;
    if (tid < BW) dcnt[tid] = pref[tid] - dcnt[tid];
    __syncthreads();
    for (int i = tid; i < cntb; i += 256) {
        unsigned p = spair[i];
        int slot = atomicAdd(&dcnt[p >> 24], 1);
        if (slot < CAP) lcol[slot] = (int)(p & 0xFFFFFFu);
    }
    __syncthreads();
    for (int i = tid; i < cntb; i += 256) col[base + i] = lcol[i];
}

// ---------------- bf16 helpers ----------------
__device__ inline unsigned pack_bf16(float a, float b) {
    unsigned ua = __float_as_uint(a), ub = __float_as_uint(b);
    ua = (ua + 0x7fffu + ((ua >> 16) & 1u)) >> 16;
    ub = (ub + 0x7fffu + ((ub >> 16) & 1u)) >> 16;
    return ua | (ub << 16);
}
__device__ inline float bflo(unsigned u) { return __uint_as_float(u << 16); }
__device__ inline float bfhi(unsigned u) { return __uint_as_float(u & 0xFFFF0000u); }

// ---------------- W pre-pack (3 weights, one launch) ----------------
__global__ __launch_bounds__(256) void wprep3_kernel(const float* __restrict__ W1, const float* __restrict__ W2,
                                                     const float* __restrict__ W3, uint4* __restrict__ Wb) {
    const float* W = (blockIdx.x == 0) ? W1 : (blockIdx.x == 1) ? W2 : W3;
    uint4* o = Wb + (size_t)blockIdx.x * 2048;
    int tid = threadIdx.x;
#pragma unroll
    for (int it = 0; it < 8; ++it) {
        int item = it * 256 + tid;          // 0..2047
        int lane = item & 63;
        int kbjt = item >> 6;               // jt*4 + kb
        int kb = kbjt & 3, jt = kbjt >> 2;
        int k0 = kb * 32 + (lane >> 4) * 8;
        int j = jt * 16 + (lane & 15);
        unsigned p[4];
#pragma unroll
        for (int q = 0; q < 4; ++q)
            p[q] = pack_bf16(W[(size_t)(k0 + 2 * q) * NF + j], W[(size_t)(k0 + 2 * q + 1) * NF + j]);
        o[item] = make_uint4(p[0], p[1], p[2], p[3]);
    }
}

// ---------------- MFMA GEMM: hs[i] = bf16( (A[i] @ W) * dis[i] ) ----------------
__global__ __launch_bounds__(256) void mm_mfma_kernel(const void* __restrict__ A, int a_fp32,
                                                      const uint4* __restrict__ Wb,
                                                      const float* __restrict__ dis,
                                                      unsigned* __restrict__ hs, int n) {
    int tid = threadIdx.x;
    int wave = tid >> 6, lane = tid & 63;
    int r0 = blockIdx.x * 64 + wave * 16;
    if (r0 >= n) return;
    int lrow = lane & 15, lk = lane >> 4;
    int arow = min(r0 + lrow, n - 1);

    f32x4 acc[8];
#pragma unroll
    for (int j = 0; j < 8; ++j) acc[j] = (f32x4){0.f, 0.f, 0.f, 0.f};

    U4S8 af[4];
    if (a_fp32) {
        const float* Af = (const float*)A;
#pragma unroll
        for (int kb = 0; kb < 4; ++kb) {
            const float* p = Af + (size_t)arow * NF + kb * 32 + lk * 8;
            float4 x0 = *(const float4*)p;
            float4 x1 = *(const float4*)(p + 4);
            af[kb].u = make_uint4(pack_bf16(x0.x, x0.y), pack_bf16(x0.z, x0.w),
                                  pack_bf16(x1.x, x1.y), pack_bf16(x1.z, x1.w));
        }
    } else {
        const unsigned* Ab = (const unsigned*)A;
#pragma unroll
        for (int kb = 0; kb < 4; ++kb)
            af[kb].u = *(const uint4*)(Ab + (size_t)arow * NFU + kb * 16 + lk * 4);
    }

#pragma unroll
    for (int kb = 0; kb < 4; ++kb) {
#pragma unroll
        for (int jt = 0; jt < 8; ++jt) {
            U4S8 wf;
            wf.u = Wb[(jt * 4 + kb) * 64 + lane];
            acc[jt] = __builtin_amdgcn_mfma_f32_16x16x32_bf16(wf.s, af[kb].s, acc[jt], 0, 0, 0);
        }
    }

    if (r0 + lrow < n) {
        float dv = dis[r0 + lrow];
        unsigned* orow = hs + (size_t)(r0 + lrow) * NFU;
#pragma unroll
        for (int jt = 0; jt < 8; ++jt) {
            unsigned p0 = pack_bf16(acc[jt][0] * dv, acc[jt][1] * dv);
            unsigned p1 = pack_bf16(acc[jt][2] * dv, acc[jt][3] * dv);
            *(uint2*)(orow + jt * 8 + lk * 2) = make_uint2(p0, p1);
        }
    }
}

// ---------------- SpMM: one 16-lane group per dst row (4 rows/wave), no cross-group reduce ----------------
#define SPACC(v)                                              \
    { a0 += (f32x2){bflo((v).x), bfhi((v).x)};                \
      a1 += (f32x2){bflo((v).y), bfhi((v).y)};                \
      a2 += (f32x2){bflo((v).z), bfhi((v).z)};                \
      a3 += (f32x2){bflo((v).w), bfhi((v).w)}; }

__global__ __launch_bounds__(256) void spmm_kernel(const unsigned* __restrict__ hs, const int* __restrict__ rowptr,
                                                   const int* __restrict__ col, const float* __restrict__ dis,
                                                   const float* __restrict__ b, unsigned* __restrict__ outb,
                                                   int n, int do_relu) {
    int row = (blockIdx.x * blockDim.x + threadIdx.x) >> 4;
    int fl = threadIdx.x & 15;
    int gbase = threadIdx.x & 48;        // group base within the wave (lanes gbase..gbase+15)
    if (row >= n) return;
    int s = rowptr[row], e = rowptr[row + 1];
    int deg = e - s;

    // init accumulators from self-loop row (all 16 lanes useful)
    const unsigned* hsf = hs + fl * 4;
    uint4 sv = *(const uint4*)(hsf + (size_t)row * NFU);
    f32x2 a0 = {bflo(sv.x), bfhi(sv.x)};
    f32x2 a1 = {bflo(sv.y), bfhi(sv.y)};
    f32x2 a2 = {bflo(sv.z), bfhi(sv.z)};
    f32x2 a3 = {bflo(sv.w), bfhi(sv.w)};

    for (int jb = 0; jb < deg; jb += 16) {
        int m = min(16, deg - jb);
        int cidx = col[s + jb + ((fl < m) ? fl : (m - 1))];   // 16 indices, one per lane
        int j = 0;
        for (; j + 2 <= m; j += 2) {     // 2 gathers in flight; bpermute shared by 4 groups
            int c0 = __shfl(cidx, gbase + j);
            int c1 = __shfl(cidx, gbase + j + 1);
            uint4 v0 = *(const uint4*)(hsf + (size_t)c0 * NFU);
            uint4 v1 = *(const uint4*)(hsf + (size_t)c1 * NFU);
            SPACC(v0);
            SPACC(v1);
        }
        if (j < m) {
            int c0 = __shfl(cidx, gbase + j);
            uint4 v0 = *(const uint4*)(hsf + (size_t)c0 * NFU);
            SPACC(v0);
        }
    }

    float d = dis[row];
    float4 bb0 = *(const float4*)(b + fl * 8);
    float4 bb1 = *(const float4*)(b + fl * 8 + 4);
    float o[8];
    o[0] = fmaf(d, a0[0], bb0.x); o[1] = fmaf(d, a0[1], bb0.y);
    o[2] = fmaf(d, a1[0], bb0.z); o[3] = fmaf(d, a1[1], bb0.w);
    o[4] = fmaf(d, a2[0], bb1.x); o[5] = fmaf(d, a2[1], bb1.y);
    o[6] = fmaf(d, a3[0], bb1.z); o[7] = fmaf(d, a3[1], bb1.w);
    if (do_relu) {
#pragma unroll
        for (int k = 0; k < 8; ++k) o[k] = fmaxf(o[k], 0.f);
    }
    unsigned q0 = pack_bf16(o[0], o[1]);
    unsigned q1 = pack_bf16(o[2], o[3]);
    unsigned q2 = pack_bf16(o[4], o[5]);
    unsigned q3 = pack_bf16(o[6], o[7]);
    *(uint4*)(outb + (size_t)row * NFU + fl * 4) = make_uint4(q0, q1, q2, q3);
}

// ---------------- graph boundaries from sorted batch ----------------
__global__ void gbounds_kernel(const int* __restrict__ batch, const int* __restrict__ mode,
                               int* __restrict__ gstart, int n, int G) {
    int m = *mode;
    int i = blockIdx.x * blockDim.x + threadIdx.x;
    if (i >= n) return;
    int g1 = m ? batch[2 * i] : batch[i];
    int g2 = (i == n - 1) ? G : (m ? batch[2 * (i + 1)] : batch[i + 1]);
    if ((unsigned)g1 > (unsigned)G) g1 = G;
    if ((unsigned)g2 > (unsigned)G) g2 = G;
    if (i == 0) for (int g = 0; g <= g1; ++g) gstart[g] = 0;
    for (int g = g1 + 1; g <= g2; ++g) gstart[g] = i + 1;
}

// ---------------- fused mean-pool + head: 4 blocks per graph, atomic partials ----------------
__global__ __launch_bounds__(256) void poolhead_kernel(const unsigned* __restrict__ h, const int* __restrict__ gstart,
                                                       const float* __restrict__ Wl, const float* __restrict__ bl,
                                                       float* __restrict__ out, int G) {
    __shared__ float sacc[16][16][8];   // 8 KB
    int g = blockIdx.x >> 2, sub = blockIdx.x & 3;
    int s0 = gstart[g], e0 = gstart[g + 1];
    int cnt = e0 - s0;
    int per = (cnt + 3) >> 2;
    int s = s0 + sub * per;
    int e = min(s + per, e0);
    int tid = threadIdx.x;
    int rg = tid >> 4, fl = tid & 15;

    float acc[8] = {0.f, 0.f, 0.f, 0.f, 0.f, 0.f, 0.f, 0.f};
    for (int i = s + rg; i < e; i += 16) {
        uint4 v = *(const uint4*)(h + (size_t)i * NFU + fl * 4);
        acc[0] += bflo(v.x); acc[1] += bfhi(v.x);
        acc[2] += bflo(v.y); acc[3] += bfhi(v.y);
        acc[4] += bflo(v.z); acc[5] += bfhi(v.z);
        acc[6] += bflo(v.w); acc[7] += bfhi(v.w);
    }
#pragma unroll
    for (int k = 0; k < 8; ++k) sacc[rg][fl][k] = acc[k];
    __syncthreads();
    if (tid < 16) {
        float t[8] = {0.f, 0.f, 0.f, 0.f, 0.f, 0.f, 0.f, 0.f};
        for (int r = 0; r < 16; ++r)
#pragma unroll
            for (int k = 0; k < 8; ++k) t[k] += sacc[r][tid][k];
        float inv = 1.0f / fmaxf((float)cnt, 1.0f);
        float o0 = 0.f, o1 = 0.f;
#pragma unroll
        for (int k = 0; k < 8; ++k) {
            int f = tid * 8 + k;
            o0 += t[k] * inv * Wl[f * 2];
            o1 += t[k] * inv * Wl[f * 2 + 1];
        }
#pragma unroll
        for (int off2 = 8; off2; off2 >>= 1) {
            o0 += __shfl_down(o0, off2, 16);
            o1 += __shfl_down(o1, off2, 16);
        }
        if (tid == 0) {
            if (sub == 0) { o0 += bl[0]; o1 += bl[1]; }
            atomicAdd(&out[g * 2 + 0], o0);
            atomicAdd(&out[g * 2 + 1], o1);
        }
    }
}

extern "C" void kernel_launch(void* const* d_in, const int* in_sizes, int n_in,
                              void* d_out, int out_size, void* d_ws, size_t ws_size,
                              hipStream_t stream) {
    const float* x  = (const float*)d_in[0];
    const int*   ei = (const int*)d_in[1];
    const int*   bt = (const int*)d_in[2];
    const float* W1 = (const float*)d_in[3];
    const float* b1 = (const float*)d_in[4];
    const float* W2 = (const float*)d_in[5];
    const float* b2 = (const float*)d_in[6];
    const float* W3 = (const float*)d_in[7];
    const float* b3 = (const float*)d_in[8];
    const float* Wl = (const float*)d_in[9];
    const float* bl = (const float*)d_in[10];
    float* out = (float*)d_out;

    const int n  = in_sizes[2];        // 100000 nodes
    const int ne = in_sizes[1] / 2;    // 1600000 edges
    const int G  = out_size / 2;       // 512 graphs
    const int K  = (n + BW - 1) / BW;  // 782 buckets
    const int nchunks = (ne + CHUNK - 1) / CHUNK;

    size_t off = 0;
    auto alloc = [&](size_t bytes) { size_t o = off; off += (bytes + 255) & ~(size_t)255; return o; };
    char* ws = (char*)d_ws;
    unsigned* hB     = (unsigned*)(ws + alloc((size_t)n * NFU * 4));  // bf16 node features
    unsigned* hsB    = (unsigned*)(ws + alloc((size_t)n * NFU * 4));  // bf16 h@W * dis
    unsigned* pairbuf= (unsigned*)(ws + alloc((size_t)ne * 4));
    int*      col    = (int*)     (ws + alloc((size_t)ne * 4));
    int*      rowptr = (int*)     (ws + alloc((size_t)(n + 1) * 4));
    float*    dis    = (float*)   (ws + alloc((size_t)n * 4));
    int*      btotal = (int*)     (ws + alloc((size_t)(K + 1) * 4));
    int*      bbase  = (int*)     (ws + alloc((size_t)(K + 1) * 4));
    int*      gcur   = (int*)     (ws + alloc((size_t)(K + 1) * 4));
    int*      gstart = (int*)     (ws + alloc((size_t)(G + 1) * 4));
    int*      blkcnt = (int*)     (ws + alloc((size_t)nchunks * K * 4));
    uint4*    Wb     = (uint4*)   (ws + alloc(3 * 2048 * 16));
    int*      mode   = (int*)     (ws + alloc(256));
    (void)ws_size;

    hipMemsetAsync(btotal, 0, (size_t)(K + 1) * 4, stream);
    hipMemsetAsync(out, 0, (size_t)out_size * 4, stream);

    detect_kernel<<<1, 64, 0, stream>>>(ei, ne, mode);
    wprep3_kernel<<<3, 256, 0, stream>>>(W1, W2, W3, Wb);

    // CSR build
    hist_kernel<<<nchunks, 256, 0, stream>>>(ei, ne, n, mode, btotal, blkcnt, K);
    scanK<<<1, 1024, 0, stream>>>(btotal, bbase, gcur, K);
    scatter_kernel<<<nchunks, 256, 0, stream>>>(ei, ne, n, mode, blkcnt, gcur, pairbuf, K);
    sort_kernel<<<K, 256, 0, stream>>>(pairbuf, bbase, rowptr, dis, col, n, K);
    gbounds_kernel<<<(n + 255) / 256, 256, 0, stream>>>(bt, mode, gstart, n, G);

    const int mm_grid = (n + 63) / 64;
    const int sp_grid = (n + 15) / 16;   // 16 rows per 256-thread block

    mm_mfma_kernel<<<mm_grid, 256, 0, stream>>>(x, 1, Wb, dis, hsB, n);
    spmm_kernel<<<sp_grid, 256, 0, stream>>>(hsB, rowptr, col, dis, b1, hB, n, 1);
    mm_mfma_kernel<<<mm_grid, 256, 0, stream>>>(hB, 0, Wb + 2048, dis, hsB, n);
    spmm_kernel<<<sp_grid, 256, 0, stream>>>(hsB, rowptr, col, dis, b2, hB, n, 1);
    mm_mfma_kernel<<<mm_grid, 256, 0, stream>>>(hB, 0, Wb + 4096, dis, hsB, n);
    spmm_kernel<<<sp_grid, 256, 0, stream>>>(hsB, rowptr, col, dis, b3, hB, n, 0);

    poolhead_kernel<<<G * 4, 256, 0, stream>>>(hB, gstart, Wl, bl, out, G);
}

// Round 9
// 289.710 us; speedup vs baseline: 2.8354x; 1.1072x over previous
//
#include <hip/hip_runtime.h>

#define NF 128            // feature dim
#define NFU 64            // uints per bf16 row (NF/2)
#define BW 128            // dst rows per bucket
#define KMAX 1024         // max buckets
#define CAP 3072          // max edges per bucket (mean 2048, sd 45)
#define CHUNK 8192        // edges per block in hist/scatter

typedef __attribute__((ext_vector_type(8))) short bf16x8;
typedef __attribute__((ext_vector_type(4))) float f32x4;
typedef __attribute__((ext_vector_type(2))) float f32x2;
union U4S8 { uint4 u; bf16x8 s; };

// ---------------- bf16 helpers ----------------
__device__ inline unsigned pack_bf16(float a, float b) {
    unsigned ua = __float_as_uint(a), ub = __float_as_uint(b);
    ua = (ua + 0x7fffu + ((ua >> 16) & 1u)) >> 16;
    ub = (ub + 0x7fffu + ((ub >> 16) & 1u)) >> 16;
    return ua | (ub << 16);
}
__device__ inline float bflo(unsigned u) { return __uint_as_float(u << 16); }
__device__ inline float bfhi(unsigned u) { return __uint_as_float(u & 0xFFFF0000u); }

// ---------------- detect int layout + zero btotal/out (one launch) ----------------
__global__ void detect_init_kernel(const int* __restrict__ ei, int ne, int* __restrict__ mode,
                                   int* __restrict__ btotal, int Kp1, float* __restrict__ out, int osz) {
    if (blockIdx.x == 0) {
        if (threadIdx.x == 0) {
            int step = ne / 32; if (step < 1) step = 1;
            int all0 = 1;
            for (int k = 0; k < 16; ++k) {
                int idx = 2 * k * step + 1;
                if (ei[idx] != 0) { all0 = 0; break; }
            }
            *mode = all0;                        // 1 = int64 words, 0 = int32
        }
    } else {
        int i = (blockIdx.x - 1) * 256 + threadIdx.x;
        int stride = 8 * 256;
        for (int k = i; k < Kp1; k += stride) btotal[k] = 0;
        for (int k = i; k < osz; k += stride) out[k] = 0.f;
    }
}

// ---------------- W pre-pack (blocks 0-2) + graph bounds (blocks 3+) ----------------
__global__ __launch_bounds__(256) void wprep_gbounds_kernel(const float* __restrict__ W1, const float* __restrict__ W2,
                                                            const float* __restrict__ W3, uint4* __restrict__ Wb,
                                                            const int* __restrict__ batch, const int* __restrict__ mode,
                                                            int* __restrict__ gstart, int n, int G) {
    int tid = threadIdx.x;
    if (blockIdx.x < 3) {
        const float* W = (blockIdx.x == 0) ? W1 : (blockIdx.x == 1) ? W2 : W3;
        uint4* o = Wb + (size_t)blockIdx.x * 2048;
#pragma unroll
        for (int it = 0; it < 8; ++it) {
            int item = it * 256 + tid;          // 0..2047
            int lane = item & 63;
            int kbjt = item >> 6;               // jt*4 + kb
            int kb = kbjt & 3, jt = kbjt >> 2;
            int k0 = kb * 32 + (lane >> 4) * 8;
            int j = jt * 16 + (lane & 15);
            unsigned p[4];
#pragma unroll
            for (int q = 0; q < 4; ++q)
                p[q] = pack_bf16(W[(size_t)(k0 + 2 * q) * NF + j], W[(size_t)(k0 + 2 * q + 1) * NF + j]);
            o[item] = make_uint4(p[0], p[1], p[2], p[3]);
        }
    } else {
        int m = *mode;
        int i = (blockIdx.x - 3) * 256 + tid;
        if (i >= n) return;
        int g1 = m ? batch[2 * i] : batch[i];
        int g2 = (i == n - 1) ? G : (m ? batch[2 * (i + 1)] : batch[i + 1]);
        if ((unsigned)g1 > (unsigned)G) g1 = G;
        if ((unsigned)g2 > (unsigned)G) g2 = G;
        if (i == 0) for (int g = 0; g <= g1; ++g) gstart[g] = 0;
        for (int g = g1 + 1; g <= g2; ++g) gstart[g] = i + 1;
    }
}

// ---------------- pass 1a: per-bucket edge counts (+ per-block counts saved) ----------------
__global__ __launch_bounds__(256) void hist_kernel(const int* __restrict__ ei, int ne, int n,
                                                   const int* __restrict__ mode, int* __restrict__ btotal,
                                                   int* __restrict__ blkcnt, int K) {
    __shared__ int hist[KMAX];
    int m = *mode;
    int tid = threadIdx.x;
    for (int k = tid; k < K; k += 256) hist[k] = 0;
    __syncthreads();
    int base = blockIdx.x * CHUNK;
    int end = min(base + CHUNK, ne);
    for (int e = base + tid; e < end; e += 256) {
        int dst = m ? ei[2 * (ne + e)] : ei[ne + e];
        if ((unsigned)dst < (unsigned)n) atomicAdd(&hist[dst >> 7], 1);
    }
    __syncthreads();
    for (int k = tid; k < K; k += 256) {
        int c = hist[k];
        blkcnt[(size_t)blockIdx.x * K + k] = c;
        if (c) atomicAdd(&btotal[k], c);
    }
}

// ---------------- pass 1b: prefix over bucket totals ----------------
__global__ __launch_bounds__(1024) void scanK(const int* __restrict__ btotal, int* __restrict__ bbase,
                                              int* __restrict__ gcur, int K) {
    __shared__ int sm[1024];
    int tid = threadIdx.x;
    int v = (tid < K) ? btotal[tid] : 0;
    sm[tid] = v;
    __syncthreads();
    for (int off = 1; off < 1024; off <<= 1) {
        int t = (tid >= off) ? sm[tid - off] : 0;
        __syncthreads();
        sm[tid] += t;
        __syncthreads();
    }
    if (tid < K) {
        int excl = sm[tid] - v;
        bbase[tid] = excl;
        gcur[tid] = excl;
        if (tid == K - 1) bbase[K] = sm[tid];
    }
}

// ---------------- pass 1c: single-pass bucketed scatter (reserve from saved counts) ----------------
__global__ __launch_bounds__(256) void scatter_kernel(const int* __restrict__ ei, int ne, int n,
                                                      const int* __restrict__ mode, const int* __restrict__ blkcnt,
                                                      int* __restrict__ gcur, unsigned* __restrict__ pairbuf,
                                                      int K) {
    __shared__ int cur[KMAX];
    int m = *mode;
    int tid = threadIdx.x;
    for (int k = tid; k < K; k += 256) {
        int c = blkcnt[(size_t)blockIdx.x * K + k];
        cur[k] = c ? atomicAdd(&gcur[k], c) : 0;
    }
    __syncthreads();
    int base = blockIdx.x * CHUNK;
    int end = min(base + CHUNK, ne);
    for (int e = base + tid; e < end; e += 256) {
        int src = m ? ei[2 * e] : ei[e];
        int dst = m ? ei[2 * (ne + e)] : ei[ne + e];
        if ((unsigned)dst >= (unsigned)n || (unsigned)src >= (unsigned)n) continue;
        int pos = atomicAdd(&cur[dst >> 7], 1);
        pairbuf[pos] = (unsigned)src | ((unsigned)(dst & (BW - 1)) << 24);   // n < 2^24
    }
}

// ---------------- pass 2: per-bucket counting sort + degree/rowptr/dis ----------------
__global__ __launch_bounds__(256) void sort_kernel(const unsigned* __restrict__ pairbuf,
                                                   const int* __restrict__ bbase,
                                                   int* __restrict__ rowptr, float* __restrict__ dis,
                                                   int* __restrict__ col, int n, int K) {
    __shared__ unsigned spair[CAP];   // 12 KB
    __shared__ int lcol[CAP];         // 12 KB
    __shared__ int dcnt[BW];
    __shared__ int pref[BW];
    int tid = threadIdx.x;
    int b = blockIdx.x;
    int r0 = b * BW;
    int base = bbase[b];
    int end = bbase[b + 1];
    int cntb = end - base;
    if (cntb > CAP) cntb = CAP;

    for (int i = tid; i < cntb; i += 256) spair[i] = pairbuf[base + i];
    if (tid < BW) dcnt[tid] = 0;
    __syncthreads();
    for (int i = tid; i < cntb; i += 256) atomicAdd(&dcnt[spair[i] >> 24], 1);
    __syncthreads();
    if (tid < BW) pref[tid] = dcnt[tid];
    __syncthreads();
    for (int off = 1; off < BW; off <<= 1) {
        int t = (tid < BW && tid >= off) ? pref[tid - off] : 0;
        __syncthreads();
        if (tid < BW) pref[tid] += t;
        __syncthreads();
    }
    if (tid < BW) {
        int d = r0 + tid;
        if (d < n) {
            int excl = pref[tid] - dcnt[tid];
            rowptr[d] = base + excl;
            dis[d] = rsqrtf((float)(dcnt[tid] + 1));
        }
    }
    if (b == K - 1 && tid == 0) rowptr[n] = end;
    if (tid < BW) dcnt[tid] = pref[tid] - dcnt[tid];
    __syncthreads();
    for (int i = tid; i < cntb; i += 256) {
        unsigned p = spair[i];
        int slot = atomicAdd(&dcnt[p >> 24], 1);
        if (slot < CAP) lcol[slot] = (int)(p & 0xFFFFFFu);
    }
    __syncthreads();
    for (int i = tid; i < cntb; i += 256) col[base + i] = lcol[i];
}

// ---------------- MFMA GEMM (layer 1, fp32 input): hs[i] = bf16( (A[i] @ W) * dis[i] ) ----------------
__global__ __launch_bounds__(256) void mm_mfma_kernel(const float* __restrict__ Af,
                                                      const uint4* __restrict__ Wb,
                                                      const float* __restrict__ dis,
                                                      unsigned* __restrict__ hs, int n) {
    int tid = threadIdx.x;
    int wave = tid >> 6, lane = tid & 63;
    int r0 = blockIdx.x * 64 + wave * 16;
    if (r0 >= n) return;
    int lrow = lane & 15, lk = lane >> 4;
    int arow = min(r0 + lrow, n - 1);

    f32x4 acc[8];
#pragma unroll
    for (int j = 0; j < 8; ++j) acc[j] = (f32x4){0.f, 0.f, 0.f, 0.f};

    U4S8 af[4];
#pragma unroll
    for (int kb = 0; kb < 4; ++kb) {
        const float* p = Af + (size_t)arow * NF + kb * 32 + lk * 8;
        float4 x0 = *(const float4*)p;
        float4 x1 = *(const float4*)(p + 4);
        af[kb].u = make_uint4(pack_bf16(x0.x, x0.y), pack_bf16(x0.z, x0.w),
                              pack_bf16(x1.x, x1.y), pack_bf16(x1.z, x1.w));
    }

#pragma unroll
    for (int kb = 0; kb < 4; ++kb) {
#pragma unroll
        for (int jt = 0; jt < 8; ++jt) {
            U4S8 wf;
            wf.u = Wb[(jt * 4 + kb) * 64 + lane];
            acc[jt] = __builtin_amdgcn_mfma_f32_16x16x32_bf16(wf.s, af[kb].s, acc[jt], 0, 0, 0);
        }
    }

    if (r0 + lrow < n) {
        float dv = dis[r0 + lrow];
        unsigned* orow = hs + (size_t)(r0 + lrow) * NFU;
#pragma unroll
        for (int jt = 0; jt < 8; ++jt) {
            unsigned p0 = pack_bf16(acc[jt][0] * dv, acc[jt][1] * dv);
            unsigned p1 = pack_bf16(acc[jt][2] * dv, acc[jt][3] * dv);
            *(uint2*)(orow + jt * 8 + lk * 2) = make_uint2(p0, p1);
        }
    }
}

// ---------------- shared gather core: one 16-lane group per dst row, 4-deep staging ----------------
#define SPACC(v)                                              \
    { a0 += (f32x2){bflo((v).x), bfhi((v).x)};                \
      a1 += (f32x2){bflo((v).y), bfhi((v).y)};                \
      a2 += (f32x2){bflo((v).z), bfhi((v).z)};                \
      a3 += (f32x2){bflo((v).w), bfhi((v).w)}; }

__device__ inline void gather_row(const unsigned* __restrict__ hsf, const int* __restrict__ col,
                                  int s, int e, int row, int fl, int gbase,
                                  f32x2& a0, f32x2& a1, f32x2& a2, f32x2& a3) {
    uint4 sv = *(const uint4*)(hsf + (size_t)row * NFU);   // self-loop
    a0 = (f32x2){bflo(sv.x), bfhi(sv.x)};
    a1 = (f32x2){bflo(sv.y), bfhi(sv.y)};
    a2 = (f32x2){bflo(sv.z), bfhi(sv.z)};
    a3 = (f32x2){bflo(sv.w), bfhi(sv.w)};
    int deg = e - s;
    for (int jb = 0; jb < deg; jb += 16) {
        int m = min(16, deg - jb);
        int cidx = col[s + jb + ((fl < m) ? fl : (m - 1))];
        int j = 0;
        for (; j + 4 <= m; j += 4) {     // 4 gathers in flight
            int c0 = __shfl(cidx, gbase + j);
            int c1 = __shfl(cidx, gbase + j + 1);
            int c2 = __shfl(cidx, gbase + j + 2);
            int c3 = __shfl(cidx, gbase + j + 3);
            uint4 v0 = *(const uint4*)(hsf + (size_t)c0 * NFU);
            uint4 v1 = *(const uint4*)(hsf + (size_t)c1 * NFU);
            uint4 v2 = *(const uint4*)(hsf + (size_t)c2 * NFU);
            uint4 v3 = *(const uint4*)(hsf + (size_t)c3 * NFU);
            SPACC(v0); SPACC(v1); SPACC(v2); SPACC(v3);
        }
        for (; j < m; ++j) {
            int c0 = __shfl(cidx, gbase + j);
            uint4 v0 = *(const uint4*)(hsf + (size_t)c0 * NFU);
            SPACC(v0);
        }
    }
}

// ---------------- standalone SpMM (layer 3): h3 = agg + b (no relu), bf16 out ----------------
__global__ __launch_bounds__(256) void spmm_kernel(const unsigned* __restrict__ hs, const int* __restrict__ rowptr,
                                                   const int* __restrict__ col, const float* __restrict__ dis,
                                                   const float* __restrict__ b, unsigned* __restrict__ outb,
                                                   int n) {
    int row = (blockIdx.x * blockDim.x + threadIdx.x) >> 4;
    int fl = threadIdx.x & 15;
    int gbase = threadIdx.x & 48;
    if (row >= n) return;
    int s = rowptr[row], e = rowptr[row + 1];
    const unsigned* hsf = hs + fl * 4;
    f32x2 a0, a1, a2, a3;
    gather_row(hsf, col, s, e, row, fl, gbase, a0, a1, a2, a3);

    float d = dis[row];
    float4 bb0 = *(const float4*)(b + fl * 8);
    float4 bb1 = *(const float4*)(b + fl * 8 + 4);
    float o[8];
    o[0] = fmaf(d, a0[0], bb0.x); o[1] = fmaf(d, a0[1], bb0.y);
    o[2] = fmaf(d, a1[0], bb0.z); o[3] = fmaf(d, a1[1], bb0.w);
    o[4] = fmaf(d, a2[0], bb1.x); o[5] = fmaf(d, a2[1], bb1.y);
    o[6] = fmaf(d, a3[0], bb1.z); o[7] = fmaf(d, a3[1], bb1.w);
    unsigned q0 = pack_bf16(o[0], o[1]);
    unsigned q1 = pack_bf16(o[2], o[3]);
    unsigned q2 = pack_bf16(o[4], o[5]);
    unsigned q3 = pack_bf16(o[6], o[7]);
    *(uint4*)(outb + (size_t)row * NFU + fl * 4) = make_uint4(q0, q1, q2, q3);
}

// ---------------- fused SpMM(+bias+relu) + next-layer MFMA GEMM ----------------
// Block = 256 threads = 16 rows. Phase 1: 16-lane group per row -> LDS.
// Phase 2: lanes 0..63 (wave 0) run the 16-row GEMM, write hs_out = (h@W)*dis.
__global__ __launch_bounds__(256) void spmm_mm_kernel(const unsigned* __restrict__ hs_in,
                                                      const int* __restrict__ rowptr, const int* __restrict__ col,
                                                      const float* __restrict__ dis, const float* __restrict__ b,
                                                      const uint4* __restrict__ Wb,
                                                      unsigned* __restrict__ hs_out, int n) {
    __shared__ unsigned lh[16][65];   // padded: +1 uint per row kills MFMA-read bank conflicts
    int tid = threadIdx.x;
    int rloc = tid >> 4;
    int row0 = blockIdx.x * 16;
    int row = row0 + rloc;
    int fl = tid & 15;
    int gbase = tid & 48;

    if (row < n) {
        int s = rowptr[row], e = rowptr[row + 1];
        const unsigned* hsf = hs_in + fl * 4;
        f32x2 a0, a1, a2, a3;
        gather_row(hsf, col, s, e, row, fl, gbase, a0, a1, a2, a3);

        float d = dis[row];
        float4 bb0 = *(const float4*)(b + fl * 8);
        float4 bb1 = *(const float4*)(b + fl * 8 + 4);
        float o[8];
        o[0] = fmaxf(fmaf(d, a0[0], bb0.x), 0.f); o[1] = fmaxf(fmaf(d, a0[1], bb0.y), 0.f);
        o[2] = fmaxf(fmaf(d, a1[0], bb0.z), 0.f); o[3] = fmaxf(fmaf(d, a1[1], bb0.w), 0.f);
        o[4] = fmaxf(fmaf(d, a2[0], bb1.x), 0.f); o[5] = fmaxf(fmaf(d, a2[1], bb1.y), 0.f);
        o[6] = fmaxf(fmaf(d, a3[0], bb1.z), 0.f); o[7] = fmaxf(fmaf(d, a3[1], bb1.w), 0.f);
        lh[rloc][fl * 4 + 0] = pack_bf16(o[0], o[1]);
        lh[rloc][fl * 4 + 1] = pack_bf16(o[2], o[3]);
        lh[rloc][fl * 4 + 2] = pack_bf16(o[4], o[5]);
        lh[rloc][fl * 4 + 3] = pack_bf16(o[6], o[7]);
    }
    __syncthreads();

    if (tid < 64) {
        int lane = tid;
        int lrow = lane & 15, lk = lane >> 4;
        f32x4 acc[8];
#pragma unroll
        for (int j = 0; j < 8; ++j) acc[j] = (f32x4){0.f, 0.f, 0.f, 0.f};
        U4S8 af[4];
#pragma unroll
        for (int kb = 0; kb < 4; ++kb) {
            unsigned* p = &lh[lrow][kb * 16 + lk * 4];
            af[kb].u = make_uint4(p[0], p[1], p[2], p[3]);
        }
#pragma unroll
        for (int kb = 0; kb < 4; ++kb) {
#pragma unroll
            for (int jt = 0; jt < 8; ++jt) {
                U4S8 wf;
                wf.u = Wb[(jt * 4 + kb) * 64 + lane];
                acc[jt] = __builtin_amdgcn_mfma_f32_16x16x32_bf16(wf.s, af[kb].s, acc[jt], 0, 0, 0);
            }
        }
        int orow_i = row0 + lrow;
        if (orow_i < n) {
            float dv = dis[orow_i];
            unsigned* orow = hs_out + (size_t)orow_i * NFU;
#pragma unroll
            for (int jt = 0; jt < 8; ++jt) {
                unsigned p0 = pack_bf16(acc[jt][0] * dv, acc[jt][1] * dv);
                unsigned p1 = pack_bf16(acc[jt][2] * dv, acc[jt][3] * dv);
                *(uint2*)(orow + jt * 8 + lk * 2) = make_uint2(p0, p1);
            }
        }
    }
}

// ---------------- fused mean-pool + head: 4 blocks per graph, atomic partials ----------------
__global__ __launch_bounds__(256) void poolhead_kernel(const unsigned* __restrict__ h, const int* __restrict__ gstart,
                                                       const float* __restrict__ Wl, const float* __restrict__ bl,
                                                       float* __restrict__ out, int G) {
    __shared__ float sacc[16][16][8];   // 8 KB
    int g = blockIdx.x >> 2, sub = blockIdx.x & 3;
    int s0 = gstart[g], e0 = gstart[g + 1];
    int cnt = e0 - s0;
    int per = (cnt + 3) >> 2;
    int s = s0 + sub * per;
    int e = min(s + per, e0);
    int tid = threadIdx.x;
    int rg = tid >> 4, fl = tid & 15;

    float acc[8] = {0.f, 0.f, 0.f, 0.f, 0.f, 0.f, 0.f, 0.f};
    for (int i = s + rg; i < e; i += 16) {
        uint4 v = *(const uint4*)(h + (size_t)i * NFU + fl * 4);
        acc[0] += bflo(v.x); acc[1] += bfhi(v.x);
        acc[2] += bflo(v.y); acc[3] += bfhi(v.y);
        acc[4] += bflo(v.z); acc[5] += bfhi(v.z);
        acc[6] += bflo(v.w); acc[7] += bfhi(v.w);
    }
#pragma unroll
    for (int k = 0; k < 8; ++k) sacc[rg][fl][k] = acc[k];
    __syncthreads();
    if (tid < 16) {
        float t[8] = {0.f, 0.f, 0.f, 0.f, 0.f, 0.f, 0.f, 0.f};
        for (int r = 0; r < 16; ++r)
#pragma unroll
            for (int k = 0; k < 8; ++k) t[k] += sacc[r][tid][k];
        float inv = 1.0f / fmaxf((float)cnt, 1.0f);
        float o0 = 0.f, o1 = 0.f;
#pragma unroll
        for (int k = 0; k < 8; ++k) {
            int f = tid * 8 + k;
            o0 += t[k] * inv * Wl[f * 2];
            o1 += t[k] * inv * Wl[f * 2 + 1];
        }
#pragma unroll
        for (int off2 = 8; off2; off2 >>= 1) {
            o0 += __shfl_down(o0, off2, 16);
            o1 += __shfl_down(o1, off2, 16);
        }
        if (tid == 0) {
            if (sub == 0) { o0 += bl[0]; o1 += bl[1]; }
            atomicAdd(&out[g * 2 + 0], o0);
            atomicAdd(&out[g * 2 + 1], o1);
        }
    }
}

extern "C" void kernel_launch(void* const* d_in, const int* in_sizes, int n_in,
                              void* d_out, int out_size, void* d_ws, size_t ws_size,
                              hipStream_t stream) {
    const float* x  = (const float*)d_in[0];
    const int*   ei = (const int*)d_in[1];
    const int*   bt = (const int*)d_in[2];
    const float* W1 = (const float*)d_in[3];
    const float* b1 = (const float*)d_in[4];
    const float* W2 = (const float*)d_in[5];
    const float* b2 = (const float*)d_in[6];
    const float* W3 = (const float*)d_in[7];
    const float* b3 = (const float*)d_in[8];
    const float* Wl = (const float*)d_in[9];
    const float* bl = (const float*)d_in[10];
    float* out = (float*)d_out;

    const int n  = in_sizes[2];        // 100000 nodes
    const int ne = in_sizes[1] / 2;    // 1600000 edges
    const int G  = out_size / 2;       // 512 graphs
    const int K  = (n + BW - 1) / BW;  // 782 buckets
    const int nchunks = (ne + CHUNK - 1) / CHUNK;

    size_t off = 0;
    auto alloc = [&](size_t bytes) { size_t o = off; off += (bytes + 255) & ~(size_t)255; return o; };
    char* ws = (char*)d_ws;
    unsigned* hsA    = (unsigned*)(ws + alloc((size_t)n * NFU * 4));  // bf16 ping
    unsigned* hsB    = (unsigned*)(ws + alloc((size_t)n * NFU * 4));  // bf16 pong
    unsigned* h3     = (unsigned*)(ws + alloc((size_t)n * NFU * 4));  // bf16 final conv out
    unsigned* pairbuf= (unsigned*)(ws + alloc((size_t)ne * 4));
    int*      col    = (int*)     (ws + alloc((size_t)ne * 4));
    int*      rowptr = (int*)     (ws + alloc((size_t)(n + 1) * 4));
    float*    dis    = (float*)   (ws + alloc((size_t)n * 4));
    int*      btotal = (int*)     (ws + alloc((size_t)(K + 1) * 4));
    int*      bbase  = (int*)     (ws + alloc((size_t)(K + 1) * 4));
    int*      gcur   = (int*)     (ws + alloc((size_t)(K + 1) * 4));
    int*      gstart = (int*)     (ws + alloc((size_t)(G + 1) * 4));
    int*      blkcnt = (int*)     (ws + alloc((size_t)nchunks * K * 4));
    uint4*    Wb     = (uint4*)   (ws + alloc(3 * 2048 * 16));
    int*      mode   = (int*)     (ws + alloc(256));
    (void)ws_size;

    detect_init_kernel<<<9, 256, 0, stream>>>(ei, ne, mode, btotal, K + 1, out, out_size);
    wprep_gbounds_kernel<<<3 + (n + 255) / 256, 256, 0, stream>>>(W1, W2, W3, Wb, bt, mode, gstart, n, G);

    // CSR build
    hist_kernel<<<nchunks, 256, 0, stream>>>(ei, ne, n, mode, btotal, blkcnt, K);
    scanK<<<1, 1024, 0, stream>>>(btotal, bbase, gcur, K);
    scatter_kernel<<<nchunks, 256, 0, stream>>>(ei, ne, n, mode, blkcnt, gcur, pairbuf, K);
    sort_kernel<<<K, 256, 0, stream>>>(pairbuf, bbase, rowptr, dis, col, n, K);

    const int mm_grid = (n + 63) / 64;
    const int sp_grid = (n + 15) / 16;   // 16 rows per 256-thread block

    mm_mfma_kernel<<<mm_grid, 256, 0, stream>>>(x, Wb, dis, hsA, n);
    spmm_mm_kernel<<<sp_grid, 256, 0, stream>>>(hsA, rowptr, col, dis, b1, Wb + 2048, hsB, n);
    spmm_mm_kernel<<<sp_grid, 256, 0, stream>>>(hsB, rowptr, col, dis, b2, Wb + 4096, hsA, n);
    spmm_kernel<<<sp_grid, 256, 0, stream>>>(hsA, rowptr, col, dis, b3, h3, n);

    poolhead_kernel<<<G * 4, 256, 0, stream>>>(h3, gstart, Wl, bl, out, G);
}